// Round 3
// baseline (7555.108 us; speedup 1.0000x reference)
//
#include <hip/hip_runtime.h>
#include <cmath>

typedef __bf16 bf16x8 __attribute__((ext_vector_type(8)));
typedef float f32x4 __attribute__((ext_vector_type(4)));

constexpr int N = 16384;   // rows
constexpr int D = 256;     // half feature dim
constexpr int K = 512;     // 2D
constexpr int V = 8192;    // codebook size
constexpr float TAU = 0.0625f;  // split-bf16 score error ~1e-2 worst; 6x margin

#define GLOAD16(g, l) __builtin_amdgcn_global_load_lds(                     \
    (const __attribute__((address_space(1))) void*)(g),                    \
    (__attribute__((address_space(3))) void*)(l), 16, 0, 0)

__device__ __forceinline__ unsigned short f2bf(float x) {
  union { float f; unsigned u; } v; v.f = x;
  unsigned r = v.u + 0x7fffu + ((v.u >> 16) & 1u);  // RN-even; inputs have no NaN
  return (unsigned short)(r >> 16);
}
__device__ __forceinline__ float bf2f(unsigned short b) {
  union { unsigned u; float f; } v; v.u = ((unsigned)b) << 16; return v.f;
}

// ----------------------------------------- split z (concat real|imag) to bf16 hi/lo
__global__ __launch_bounds__(256) void vq_split_z(
    const float* __restrict__ zr, const float* __restrict__ zi,
    unsigned short* __restrict__ Zh, unsigned short* __restrict__ Zl) {
  int t = blockIdx.x * 256 + threadIdx.x;   // [0, N*128)
  int n = t >> 7, c4 = t & 127, k = c4 * 4;
  const float* src = (k < D) ? zr + (size_t)n * D + k : zi + (size_t)n * D + (k - D);
  float4 v = *(const float4*)src;
  ushort4 h, l;
  h.x = f2bf(v.x); l.x = f2bf(v.x - bf2f(h.x));
  h.y = f2bf(v.y); l.y = f2bf(v.y - bf2f(h.y));
  h.z = f2bf(v.z); l.z = f2bf(v.z - bf2f(h.z));
  h.w = f2bf(v.w); l.w = f2bf(v.w - bf2f(h.w));
  *(ushort4*)&Zh[(size_t)n * K + k] = h;
  *(ushort4*)&Zl[(size_t)n * K + k] = l;
}

// --------------------------------------------------------- split w to bf16 hi/lo
__global__ __launch_bounds__(256) void vq_split_w(
    const float* __restrict__ w,
    unsigned short* __restrict__ Wh, unsigned short* __restrict__ Wl) {
  int t = blockIdx.x * 256 + threadIdx.x;   // [0, V*128)
  int vrow = t >> 7, c4 = t & 127, k = c4 * 4;
  float4 v = *(const float4*)(w + (size_t)vrow * K + k);
  ushort4 h, l;
  h.x = f2bf(v.x); l.x = f2bf(v.x - bf2f(h.x));
  h.y = f2bf(v.y); l.y = f2bf(v.y - bf2f(h.y));
  h.z = f2bf(v.z); l.z = f2bf(v.z - bf2f(h.z));
  h.w = f2bf(v.w); l.w = f2bf(v.w - bf2f(h.w));
  *(ushort4*)&Wh[(size_t)vrow * K + k] = h;
  *(ushort4*)&Wl[(size_t)vrow * K + k] = l;
}

// ---------------------------------------------------------------- w2 = ||w||^2
__global__ __launch_bounds__(256) void vq_w2(const float* __restrict__ w,
                                             double* __restrict__ w2d,
                                             float* __restrict__ w2f) {
  int v = blockIdx.x * 4 + (threadIdx.x >> 6);
  int lane = threadIdx.x & 63;
  const float4* wr = (const float4*)(w + (size_t)v * K);
  float4 a = wr[lane];
  float4 b = wr[64 + lane];
  double s = (double)a.x * a.x + (double)a.y * a.y + (double)a.z * a.z + (double)a.w * a.w +
             (double)b.x * b.x + (double)b.y * b.y + (double)b.z * b.z + (double)b.w * b.w;
#pragma unroll
  for (int off = 1; off < 64; off <<= 1) s += __shfl_xor(s, off, 64);
  if (lane == 0) { w2d[v] = s; w2f[v] = (float)s; }
}

// ------------------- pass 1: split-bf16 MFMA GEMM + per-(row, 64-col) top-2
// grid 8192: vt = bid & 63 (V/128), nt = bid >> 6 (N/128). 256 thr = 4 waves 2x2.
__global__ __launch_bounds__(256) void vq_pass1(
    const unsigned short* __restrict__ Zh, const unsigned short* __restrict__ Zl,
    const unsigned short* __restrict__ Wh, const unsigned short* __restrict__ Wl,
    const float* __restrict__ w2f,
    float* __restrict__ pm1, float* __restrict__ pm2, int* __restrict__ pi1) {
  // 4 tiles of [128 rows][32 k] bf16, 8 KiB each: Ah | Al | Bh | Bl
  __shared__ __align__(16) unsigned short smem[16384];

  const int tid = threadIdx.x;
  const int w = tid >> 6, lane = tid & 63;
  const int wr = w >> 1, wc = w & 1;
  const int tx = lane & 15, g = lane >> 4;
  const int rsub = lane >> 2, kq = lane & 3;     // staging row-sub / k-quad
  const int vt = blockIdx.x & 63, nt = blockIdx.x >> 6;
  const int rowBase = nt * 128, colBase = vt * 128;

  f32x4 acc[4][4];
#pragma unroll
  for (int m = 0; m < 4; ++m)
#pragma unroll
    for (int n = 0; n < 4; ++n) acc[m][n] = f32x4{0.f, 0.f, 0.f, 0.f};

  const int sst = (rsub >> 1) & 3;  // stage-side swizzle (pre-swizzled global src)
  const int srd = (tx >> 1) & 3;   // read-side swizzle (same involution)

  for (int kt = 0; kt < K; kt += 32) {
    __syncthreads();  // protect LDS from previous step's readers
#pragma unroll
    for (int cc = 0; cc < 2; ++cc) {
      const int c = 2 * w + cc;           // 16-row chunk, wave-uniform
      const int grow = c * 16 + rsub;
      const size_t zoff = (size_t)(rowBase + grow) * K + kt + ((kq ^ sst) << 3);
      const size_t woff = (size_t)(colBase + grow) * K + kt + ((kq ^ sst) << 3);
      GLOAD16(Zh + zoff, &smem[c * 512]);
      GLOAD16(Zl + zoff, &smem[4096 + c * 512]);
      GLOAD16(Wh + woff, &smem[8192 + c * 512]);
      GLOAD16(Wl + woff, &smem[12288 + c * 512]);
    }
    __syncthreads();  // compiler drains vmcnt before barrier

    bf16x8 ah[4], al[4], bh[4], bl[4];
#pragma unroll
    for (int m = 0; m < 4; ++m) {
      const int off = (wr * 64 + m * 16 + tx) * 32 + ((g ^ srd) << 3);
      ah[m] = *(const bf16x8*)&smem[off];
      al[m] = *(const bf16x8*)&smem[4096 + off];
    }
#pragma unroll
    for (int n = 0; n < 4; ++n) {
      const int off = (wc * 64 + n * 16 + tx) * 32 + ((g ^ srd) << 3);
      bh[n] = *(const bf16x8*)&smem[8192 + off];
      bl[n] = *(const bf16x8*)&smem[12288 + off];
    }
#pragma unroll
    for (int m = 0; m < 4; ++m)
#pragma unroll
      for (int n = 0; n < 4; ++n) {
        acc[m][n] = __builtin_amdgcn_mfma_f32_16x16x32_bf16(ah[m], bh[n], acc[m][n], 0, 0, 0);
        acc[m][n] = __builtin_amdgcn_mfma_f32_16x16x32_bf16(ah[m], bl[n], acc[m][n], 0, 0, 0);
        acc[m][n] = __builtin_amdgcn_mfma_f32_16x16x32_bf16(al[m], bh[n], acc[m][n], 0, 0, 0);
      }
  }

  // epilogue: scores = w2 - 2*dot, per-row top-2 over this wave's 64 cols
  float wcol[4];
#pragma unroll
  for (int n = 0; n < 4; ++n) wcol[n] = w2f[colBase + wc * 64 + n * 16 + tx];
  const int cb = vt * 2 + wc;

#pragma unroll
  for (int m = 0; m < 4; ++m) {
#pragma unroll
    for (int r = 0; r < 4; ++r) {
      float m1 = 3.4e38f, m2 = 3.4e38f;
      int i1 = 0;
#pragma unroll
      for (int n = 0; n < 4; ++n) {   // ascending v -> ties keep smallest index
        float s = fmaf(-2.0f, acc[m][n][r], wcol[n]);
        if (s < m1) { m2 = m1; m1 = s; i1 = colBase + wc * 64 + n * 16 + tx; }
        else m2 = fminf(m2, s);
      }
#pragma unroll
      for (int off = 1; off < 16; off <<= 1) {  // reduce 16 lanes sharing a row
        float om1 = __shfl_xor(m1, off, 64);
        float om2 = __shfl_xor(m2, off, 64);
        int oi = __shfl_xor(i1, off, 64);
        float nm2 = fminf(fmaxf(m1, om1), fminf(m2, om2));
        if (om1 < m1 || (om1 == m1 && oi < i1)) { m1 = om1; i1 = oi; }
        m2 = nm2;
      }
      if (tx == 0) {
        int row = rowBase + wr * 64 + m * 16 + g * 4 + r;
        size_t o = (size_t)row * 128 + cb;
        pm1[o] = m1; pm2[o] = m2; pi1[o] = i1;
      }
    }
  }
}

// ------------------- reduce 128 column-half partials per row -> argmin + flag
__global__ __launch_bounds__(256) void vq_reduce(
    const float* __restrict__ pm1, const float* __restrict__ pm2,
    const int* __restrict__ pi1,
    float* __restrict__ out_idx, int* __restrict__ ws_idx,
    int* __restrict__ flaglist, int* __restrict__ nflag) {
  int row = blockIdx.x * 4 + (threadIdx.x >> 6);
  int lane = threadIdx.x & 63;
  size_t b = (size_t)row * 128;
  float a1 = pm1[b + lane], a2 = pm2[b + lane];
  int ai = pi1[b + lane];
  float b1 = pm1[b + lane + 64], b2 = pm2[b + lane + 64];
  int bi = pi1[b + lane + 64];
  float nm2 = fminf(fmaxf(a1, b1), fminf(a2, b2));
  if (b1 < a1 || (b1 == a1 && bi < ai)) { a1 = b1; ai = bi; }
  a2 = nm2;
#pragma unroll
  for (int off = 1; off < 64; off <<= 1) {
    float o1 = __shfl_xor(a1, off, 64);
    float o2 = __shfl_xor(a2, off, 64);
    int oi = __shfl_xor(ai, off, 64);
    float n2 = fminf(fmaxf(a1, o1), fminf(a2, o2));
    if (o1 < a1 || (o1 == a1 && oi < ai)) { a1 = o1; ai = oi; }
    a2 = n2;
  }
  if (lane == 0) {
    out_idx[row] = (float)ai;
    ws_idx[row] = ai;
    if (a2 - a1 < TAU) {
      int slot = atomicAdd(nflag, 1);
      flaglist[slot] = row;
    }
  }
}

// ------------------------- pass 2: exact fp64 rescore for near-tie rows only
__global__ __launch_bounds__(256) void vq_fixup(
    const float* __restrict__ zr, const float* __restrict__ zi,
    const float* __restrict__ w, const double* __restrict__ w2d,
    const int* __restrict__ flaglist, const int* __restrict__ nflag,
    float* __restrict__ out_idx, int* __restrict__ ws_idx) {
  __shared__ float zrow[K];
  __shared__ double smin[256];
  __shared__ int sidx[256];
  const int tid = threadIdx.x;
  const int nf = *nflag;

  for (int f = blockIdx.x; f < nf; f += gridDim.x) {
    int row = flaglist[f];
    __syncthreads();
    for (int k = tid; k < K; k += 256)
      zrow[k] = (k < D) ? zr[(size_t)row * D + k] : zi[(size_t)row * D + (k - D)];
    __syncthreads();

    double best = 1e300;
    int bidx = 0;
    for (int v = tid; v < V; v += 256) {
      const float4* wr4 = (const float4*)(w + (size_t)v * K);
      const float4* zl4 = (const float4*)zrow;
      double dot = 0.0;
      for (int k4 = 0; k4 < K / 4; ++k4) {
        float4 a = wr4[k4];
        float4 b = zl4[k4];
        dot = fma((double)a.x, (double)b.x, dot);
        dot = fma((double)a.y, (double)b.y, dot);
        dot = fma((double)a.z, (double)b.z, dot);
        dot = fma((double)a.w, (double)b.w, dot);
      }
      double d = w2d[v] - 2.0 * dot;
      if (d < best) { best = d; bidx = v; }  // v ascending -> smallest index on ties
    }
    smin[tid] = best;
    sidx[tid] = bidx;
    __syncthreads();
    for (int s = 128; s > 0; s >>= 1) {
      if (tid < s) {
        if (smin[tid + s] < smin[tid] ||
            (smin[tid + s] == smin[tid] && sidx[tid + s] < sidx[tid])) {
          smin[tid] = smin[tid + s];
          sidx[tid] = sidx[tid + s];
        }
      }
      __syncthreads();
    }
    if (tid == 0) {
      out_idx[row] = (float)sidx[0];
      ws_idx[row] = sidx[0];
    }
  }
}

// ---------------- gather z_q, write outputs 0/1, loss, histogram for entropy
__global__ __launch_bounds__(256) void vq_gather(
    const float* __restrict__ zr, const float* __restrict__ zi,
    const float* __restrict__ w, const int* __restrict__ ws_idx,
    float* __restrict__ out0, float* __restrict__ out1,
    float* __restrict__ out2, unsigned int* __restrict__ counts) {
  int row = blockIdx.x * 4 + (threadIdx.x >> 6);
  int lane = threadIdx.x & 63;
  int idx = ws_idx[row];
  const float4* wr = (const float4*)(w + (size_t)idx * K);
  float4 q0 = wr[lane];
  float4 q1 = wr[64 + lane];
  float4 a = ((const float4*)(zr + (size_t)row * D))[lane];
  float4 b = ((const float4*)(zi + (size_t)row * D))[lane];
  ((float4*)(out0 + (size_t)row * D))[lane] = q0;
  ((float4*)(out1 + (size_t)row * D))[lane] = q1;

  float s = 0.f, dx;
  dx = q0.x - a.x; s = fmaf(dx, dx, s);
  dx = q0.y - a.y; s = fmaf(dx, dx, s);
  dx = q0.z - a.z; s = fmaf(dx, dx, s);
  dx = q0.w - a.w; s = fmaf(dx, dx, s);
  dx = q1.x - b.x; s = fmaf(dx, dx, s);
  dx = q1.y - b.y; s = fmaf(dx, dx, s);
  dx = q1.z - b.z; s = fmaf(dx, dx, s);
  dx = q1.w - b.w; s = fmaf(dx, dx, s);
#pragma unroll
  for (int off = 1; off < 64; off <<= 1) s += __shfl_xor(s, off, 64);
  if (lane == 0) {
    out2[row] = s * (1.25f / 512.f);
    atomicAdd(counts + idx, 1u);
  }
}

// ------------------------------------------------------------------- entropy
__global__ __launch_bounds__(256) void vq_entropy(const unsigned int* __restrict__ counts,
                                                  float* __restrict__ out4) {
  __shared__ double sd[256];
  int tid = threadIdx.x;
  double e = 0.0;
  for (int v = tid; v < V; v += 256) {
    double p = (double)counts[v] * (1.0 / (double)N);
    e += p * log(p + 1e-10);
  }
  sd[tid] = e;
  __syncthreads();
  for (int s = 128; s > 0; s >>= 1) {
    if (tid < s) sd[tid] += sd[tid + s];
    __syncthreads();
  }
  if (tid == 0) *out4 = -(float)sd[0];
}

// ---------------------------------------------------------------------------
extern "C" void kernel_launch(void* const* d_in, const int* in_sizes, int n_in,
                              void* d_out, int out_size, void* d_ws, size_t ws_size,
                              hipStream_t stream) {
  const float* zr = (const float*)d_in[0];
  const float* zi = (const float*)d_in[1];
  const float* w = (const float*)d_in[2];

  float* out = (float*)d_out;
  float* out0 = out;                       // z_q real   (N*D)
  float* out1 = out + (size_t)N * D;       // z_q imag   (N*D)
  float* out2 = out + (size_t)2 * N * D;   // loss       (N)
  float* out3 = out2 + N;                  // indices    (N, as float)
  float* out4 = out3 + N;                  // entropy    (1)

  // top-2 partials live in the z_q output region; vq_gather overwrites it later
  float* pm1 = out;                              // N*128 floats = 8 MiB
  float* pm2 = out + (size_t)N * 128;            // 8 MiB
  int* pi1 = (int*)(out + (size_t)2 * N * 128);  // 8 MiB

  char* ws = (char*)d_ws;
  unsigned short* Zh = (unsigned short*)ws;                          // 16 MiB
  unsigned short* Zl = (unsigned short*)(ws + (((size_t)16) << 20)); // 16 MiB
  unsigned short* Wh = (unsigned short*)(ws + (((size_t)32) << 20)); // 8 MiB
  unsigned short* Wl = (unsigned short*)(ws + (((size_t)40) << 20)); // 8 MiB
  char* ws2 = ws + (((size_t)48) << 20);
  double* w2d = (double*)ws2;                          // 64 KiB
  float* w2f = (float*)(ws2 + 65536);                  // 32 KiB
  unsigned int* counts = (unsigned int*)(ws2 + 98304); // 32 KiB
  int* ws_idx = (int*)(ws2 + 131072);                  // 64 KiB
  int* flaglist = (int*)(ws2 + 196608);                // 64 KiB
  int* nflag = (int*)(ws2 + 262144);                   // 4 B

  (void)hipMemsetAsync(counts, 0, V * sizeof(unsigned int), stream);
  (void)hipMemsetAsync(nflag, 0, sizeof(int), stream);

  vq_split_z<<<N * 128 / 256, 256, 0, stream>>>(zr, zi, Zh, Zl);
  vq_split_w<<<V * 128 / 256, 256, 0, stream>>>(w, Wh, Wl);
  vq_w2<<<V / 4, 256, 0, stream>>>(w, w2d, w2f);
  vq_pass1<<<(N / 128) * (V / 128), 256, 0, stream>>>(Zh, Zl, Wh, Wl, w2f, pm1, pm2, pi1);
  vq_reduce<<<N / 4, 256, 0, stream>>>(pm1, pm2, pi1, out3, ws_idx, flaglist, nflag);
  vq_fixup<<<128, 256, 0, stream>>>(zr, zi, w, w2d, flaglist, nflag, out3, ws_idx);
  vq_gather<<<N / 4, 256, 0, stream>>>(zr, zi, w, ws_idx, out0, out1, out2, counts);
  vq_entropy<<<1, 256, 0, stream>>>(counts, out4);
}

// Round 4
// 1031.426 us; speedup vs baseline: 7.3249x; 7.3249x over previous
//
#include <hip/hip_runtime.h>
#include <cmath>

typedef __bf16 bf16x8 __attribute__((ext_vector_type(8)));
typedef float f32x4 __attribute__((ext_vector_type(4)));

constexpr int N = 16384;   // rows
constexpr int D = 256;     // half feature dim
constexpr int K = 512;     // 2D
constexpr int V = 8192;    // codebook size
// split-bf16 score error: |2*(zl.wl + fp32 accum)| ~ 2.4e-4 at 6 sigma -> 16x margin
constexpr float TAU = 4e-3f;

#define GLOAD16(g, l) __builtin_amdgcn_global_load_lds(                     \
    (const __attribute__((address_space(1))) void*)(g),                    \
    (__attribute__((address_space(3))) void*)(l), 16, 0, 0)

__device__ __forceinline__ unsigned short f2bf(float x) {
  union { float f; unsigned u; } v; v.f = x;
  unsigned r = v.u + 0x7fffu + ((v.u >> 16) & 1u);  // RN-even; inputs have no NaN
  return (unsigned short)(r >> 16);
}
__device__ __forceinline__ float bf2f(unsigned short b) {
  union { unsigned u; float f; } v; v.u = ((unsigned)b) << 16; return v.f;
}

// ----------------------------------------- split z (concat real|imag) to bf16 hi/lo
__global__ __launch_bounds__(256) void vq_split_z(
    const float* __restrict__ zr, const float* __restrict__ zi,
    unsigned short* __restrict__ Zh, unsigned short* __restrict__ Zl) {
  int t = blockIdx.x * 256 + threadIdx.x;   // [0, N*128)
  int n = t >> 7, c4 = t & 127, k = c4 * 4;
  const float* src = (k < D) ? zr + (size_t)n * D + k : zi + (size_t)n * D + (k - D);
  float4 v = *(const float4*)src;
  ushort4 h, l;
  h.x = f2bf(v.x); l.x = f2bf(v.x - bf2f(h.x));
  h.y = f2bf(v.y); l.y = f2bf(v.y - bf2f(h.y));
  h.z = f2bf(v.z); l.z = f2bf(v.z - bf2f(h.z));
  h.w = f2bf(v.w); l.w = f2bf(v.w - bf2f(h.w));
  *(ushort4*)&Zh[(size_t)n * K + k] = h;
  *(ushort4*)&Zl[(size_t)n * K + k] = l;
}

// --------------------------------------------------------- split w to bf16 hi/lo
__global__ __launch_bounds__(256) void vq_split_w(
    const float* __restrict__ w,
    unsigned short* __restrict__ Wh, unsigned short* __restrict__ Wl) {
  int t = blockIdx.x * 256 + threadIdx.x;   // [0, V*128)
  int vrow = t >> 7, c4 = t & 127, k = c4 * 4;
  float4 v = *(const float4*)(w + (size_t)vrow * K + k);
  ushort4 h, l;
  h.x = f2bf(v.x); l.x = f2bf(v.x - bf2f(h.x));
  h.y = f2bf(v.y); l.y = f2bf(v.y - bf2f(h.y));
  h.z = f2bf(v.z); l.z = f2bf(v.z - bf2f(h.z));
  h.w = f2bf(v.w); l.w = f2bf(v.w - bf2f(h.w));
  *(ushort4*)&Wh[(size_t)vrow * K + k] = h;
  *(ushort4*)&Wl[(size_t)vrow * K + k] = l;
}

// ---------------------------------------------------------------- w2 = ||w||^2
__global__ __launch_bounds__(256) void vq_w2(const float* __restrict__ w,
                                             double* __restrict__ w2d,
                                             float* __restrict__ w2f) {
  int v = blockIdx.x * 4 + (threadIdx.x >> 6);
  int lane = threadIdx.x & 63;
  const float4* wr = (const float4*)(w + (size_t)v * K);
  float4 a = wr[lane];
  float4 b = wr[64 + lane];
  double s = (double)a.x * a.x + (double)a.y * a.y + (double)a.z * a.z + (double)a.w * a.w +
             (double)b.x * b.x + (double)b.y * b.y + (double)b.z * b.z + (double)b.w * b.w;
#pragma unroll
  for (int off = 1; off < 64; off <<= 1) s += __shfl_xor(s, off, 64);
  if (lane == 0) { w2d[v] = s; w2f[v] = (float)s; }
}

// ------------------- pass 1: split-bf16 MFMA GEMM + per-(row, 64-col) top-2
// grid 8192: vt = bid & 63 (V/128), nt = bid >> 6 (N/128). 256 thr = 4 waves 2x2.
__global__ __launch_bounds__(256) void vq_pass1(
    const unsigned short* __restrict__ Zh, const unsigned short* __restrict__ Zl,
    const unsigned short* __restrict__ Wh, const unsigned short* __restrict__ Wl,
    const float* __restrict__ w2f,
    float* __restrict__ pm1, float* __restrict__ pm2, int* __restrict__ pi1) {
  // 4 tiles of [128 rows][32 k] bf16, 8 KiB each: Ah | Al | Bh | Bl
  __shared__ __align__(16) unsigned short smem[16384];

  const int tid = threadIdx.x;
  const int w = tid >> 6, lane = tid & 63;
  const int wr = w >> 1, wc = w & 1;
  const int tx = lane & 15, g = lane >> 4;
  const int rsub = lane >> 2, kq = lane & 3;     // staging row-sub / k-quad
  const int vt = blockIdx.x & 63, nt = blockIdx.x >> 6;
  const int rowBase = nt * 128, colBase = vt * 128;

  f32x4 acc[4][4];
#pragma unroll
  for (int m = 0; m < 4; ++m)
#pragma unroll
    for (int n = 0; n < 4; ++n) acc[m][n] = f32x4{0.f, 0.f, 0.f, 0.f};

  const int sst = (rsub >> 1) & 3;  // stage-side swizzle (pre-swizzled global src)
  const int srd = (tx >> 1) & 3;   // read-side swizzle (same involution)

  for (int kt = 0; kt < K; kt += 32) {
    __syncthreads();  // protect LDS from previous step's readers
#pragma unroll
    for (int cc = 0; cc < 2; ++cc) {
      const int c = 2 * w + cc;           // 16-row chunk, wave-uniform
      const int grow = c * 16 + rsub;
      const size_t zoff = (size_t)(rowBase + grow) * K + kt + ((kq ^ sst) << 3);
      const size_t woff = (size_t)(colBase + grow) * K + kt + ((kq ^ sst) << 3);
      GLOAD16(Zh + zoff, &smem[c * 512]);
      GLOAD16(Zl + zoff, &smem[4096 + c * 512]);
      GLOAD16(Wh + woff, &smem[8192 + c * 512]);
      GLOAD16(Wl + woff, &smem[12288 + c * 512]);
    }
    __syncthreads();  // compiler drains vmcnt before barrier

    bf16x8 ah[4], al[4], bh[4], bl[4];
#pragma unroll
    for (int m = 0; m < 4; ++m) {
      const int off = (wr * 64 + m * 16 + tx) * 32 + ((g ^ srd) << 3);
      ah[m] = *(const bf16x8*)&smem[off];
      al[m] = *(const bf16x8*)&smem[4096 + off];
    }
#pragma unroll
    for (int n = 0; n < 4; ++n) {
      const int off = (wc * 64 + n * 16 + tx) * 32 + ((g ^ srd) << 3);
      bh[n] = *(const bf16x8*)&smem[8192 + off];
      bl[n] = *(const bf16x8*)&smem[12288 + off];
    }
#pragma unroll
    for (int m = 0; m < 4; ++m)
#pragma unroll
      for (int n = 0; n < 4; ++n) {
        acc[m][n] = __builtin_amdgcn_mfma_f32_16x16x32_bf16(ah[m], bh[n], acc[m][n], 0, 0, 0);
        acc[m][n] = __builtin_amdgcn_mfma_f32_16x16x32_bf16(ah[m], bl[n], acc[m][n], 0, 0, 0);
        acc[m][n] = __builtin_amdgcn_mfma_f32_16x16x32_bf16(al[m], bh[n], acc[m][n], 0, 0, 0);
      }
  }

  // epilogue: scores = w2 - 2*dot, per-row top-2 over this wave's 64 cols
  float wcol[4];
#pragma unroll
  for (int n = 0; n < 4; ++n) wcol[n] = w2f[colBase + wc * 64 + n * 16 + tx];
  const int cb = vt * 2 + wc;

#pragma unroll
  for (int m = 0; m < 4; ++m) {
#pragma unroll
    for (int r = 0; r < 4; ++r) {
      float m1 = 3.4e38f, m2 = 3.4e38f;
      int i1 = 0;
#pragma unroll
      for (int n = 0; n < 4; ++n) {   // ascending v -> ties keep smallest index
        float s = fmaf(-2.0f, acc[m][n][r], wcol[n]);
        if (s < m1) { m2 = m1; m1 = s; i1 = colBase + wc * 64 + n * 16 + tx; }
        else m2 = fminf(m2, s);
      }
#pragma unroll
      for (int off = 1; off < 16; off <<= 1) {  // reduce 16 lanes sharing a row
        float om1 = __shfl_xor(m1, off, 64);
        float om2 = __shfl_xor(m2, off, 64);
        int oi = __shfl_xor(i1, off, 64);
        float nm2 = fminf(fmaxf(m1, om1), fminf(m2, om2));
        if (om1 < m1 || (om1 == m1 && oi < i1)) { m1 = om1; i1 = oi; }
        m2 = nm2;
      }
      if (tx == 0) {
        int row = rowBase + wr * 64 + m * 16 + g * 4 + r;
        size_t o = (size_t)row * 128 + cb;
        pm1[o] = m1; pm2[o] = m2; pi1[o] = i1;
      }
    }
  }
}

// ------------------- reduce 128 column-half partials per row -> argmin + flag
__global__ __launch_bounds__(256) void vq_reduce(
    const float* __restrict__ pm1, const float* __restrict__ pm2,
    const int* __restrict__ pi1,
    float* __restrict__ out_idx, int* __restrict__ ws_idx,
    int* __restrict__ flaglist, int* __restrict__ nflag) {
  int row = blockIdx.x * 4 + (threadIdx.x >> 6);
  int lane = threadIdx.x & 63;
  size_t b = (size_t)row * 128;
  float a1 = pm1[b + lane], a2 = pm2[b + lane];
  int ai = pi1[b + lane];
  float b1 = pm1[b + lane + 64], b2 = pm2[b + lane + 64];
  int bi = pi1[b + lane + 64];
  float nm2 = fminf(fmaxf(a1, b1), fminf(a2, b2));
  if (b1 < a1 || (b1 == a1 && bi < ai)) { a1 = b1; ai = bi; }
  a2 = nm2;
#pragma unroll
  for (int off = 1; off < 64; off <<= 1) {
    float o1 = __shfl_xor(a1, off, 64);
    float o2 = __shfl_xor(a2, off, 64);
    int oi = __shfl_xor(ai, off, 64);
    float n2 = fminf(fmaxf(a1, o1), fminf(a2, o2));
    if (o1 < a1 || (o1 == a1 && oi < ai)) { a1 = o1; ai = oi; }
    a2 = n2;
  }
  if (lane == 0) {
    out_idx[row] = (float)ai;
    ws_idx[row] = ai;
    if (a2 - a1 < TAU) {
      int slot = atomicAdd(nflag, 1);
      flaglist[slot] = row;
    }
  }
}

// ------------------------- pass 2: exact fp64 rescore for near-tie rows only
// one flagged row per block; 1024 blocks grid-stride
__global__ __launch_bounds__(256) void vq_fixup(
    const float* __restrict__ zr, const float* __restrict__ zi,
    const float* __restrict__ w, const double* __restrict__ w2d,
    const int* __restrict__ flaglist, const int* __restrict__ nflag,
    float* __restrict__ out_idx, int* __restrict__ ws_idx) {
  __shared__ float zrow[K];
  __shared__ double smin[256];
  __shared__ int sidx[256];
  const int tid = threadIdx.x;
  const int nf = *nflag;

  for (int f = blockIdx.x; f < nf; f += gridDim.x) {
    int row = flaglist[f];
    __syncthreads();
    for (int k = tid; k < K; k += 256)
      zrow[k] = (k < D) ? zr[(size_t)row * D + k] : zi[(size_t)row * D + (k - D)];
    __syncthreads();

    double best = 1e300;
    int bidx = 0;
    for (int v = tid; v < V; v += 256) {
      const float4* wr4 = (const float4*)(w + (size_t)v * K);
      const float4* zl4 = (const float4*)zrow;
      double d0 = 0.0, d1 = 0.0, d2 = 0.0, d3 = 0.0;  // 4 chains for ILP
      for (int k4 = 0; k4 < K / 4; k4 += 4) {
        float4 a0 = wr4[k4], a1 = wr4[k4 + 1], a2 = wr4[k4 + 2], a3 = wr4[k4 + 3];
        float4 b0 = zl4[k4], b1 = zl4[k4 + 1], b2 = zl4[k4 + 2], b3 = zl4[k4 + 3];
        d0 = fma((double)a0.x, (double)b0.x, d0); d0 = fma((double)a0.y, (double)b0.y, d0);
        d0 = fma((double)a0.z, (double)b0.z, d0); d0 = fma((double)a0.w, (double)b0.w, d0);
        d1 = fma((double)a1.x, (double)b1.x, d1); d1 = fma((double)a1.y, (double)b1.y, d1);
        d1 = fma((double)a1.z, (double)b1.z, d1); d1 = fma((double)a1.w, (double)b1.w, d1);
        d2 = fma((double)a2.x, (double)b2.x, d2); d2 = fma((double)a2.y, (double)b2.y, d2);
        d2 = fma((double)a2.z, (double)b2.z, d2); d2 = fma((double)a2.w, (double)b2.w, d2);
        d3 = fma((double)a3.x, (double)b3.x, d3); d3 = fma((double)a3.y, (double)b3.y, d3);
        d3 = fma((double)a3.z, (double)b3.z, d3); d3 = fma((double)a3.w, (double)b3.w, d3);
      }
      double d = w2d[v] - 2.0 * ((d0 + d1) + (d2 + d3));
      if (d < best) { best = d; bidx = v; }  // v ascending -> smallest index on ties
    }
    smin[tid] = best;
    sidx[tid] = bidx;
    __syncthreads();
    for (int s = 128; s > 0; s >>= 1) {
      if (tid < s) {
        if (smin[tid + s] < smin[tid] ||
            (smin[tid + s] == smin[tid] && sidx[tid + s] < sidx[tid])) {
          smin[tid] = smin[tid + s];
          sidx[tid] = sidx[tid + s];
        }
      }
      __syncthreads();
    }
    if (tid == 0) {
      out_idx[row] = (float)sidx[0];
      ws_idx[row] = sidx[0];
    }
    __syncthreads();
  }
}

// ---------------- gather z_q, write outputs 0/1, loss, histogram for entropy
__global__ __launch_bounds__(256) void vq_gather(
    const float* __restrict__ zr, const float* __restrict__ zi,
    const float* __restrict__ w, const int* __restrict__ ws_idx,
    float* __restrict__ out0, float* __restrict__ out1,
    float* __restrict__ out2, unsigned int* __restrict__ counts) {
  int row = blockIdx.x * 4 + (threadIdx.x >> 6);
  int lane = threadIdx.x & 63;
  int idx = ws_idx[row];
  const float4* wr = (const float4*)(w + (size_t)idx * K);
  float4 q0 = wr[lane];
  float4 q1 = wr[64 + lane];
  float4 a = ((const float4*)(zr + (size_t)row * D))[lane];
  float4 b = ((const float4*)(zi + (size_t)row * D))[lane];
  ((float4*)(out0 + (size_t)row * D))[lane] = q0;
  ((float4*)(out1 + (size_t)row * D))[lane] = q1;

  float s = 0.f, dx;
  dx = q0.x - a.x; s = fmaf(dx, dx, s);
  dx = q0.y - a.y; s = fmaf(dx, dx, s);
  dx = q0.z - a.z; s = fmaf(dx, dx, s);
  dx = q0.w - a.w; s = fmaf(dx, dx, s);
  dx = q1.x - b.x; s = fmaf(dx, dx, s);
  dx = q1.y - b.y; s = fmaf(dx, dx, s);
  dx = q1.z - b.z; s = fmaf(dx, dx, s);
  dx = q1.w - b.w; s = fmaf(dx, dx, s);
#pragma unroll
  for (int off = 1; off < 64; off <<= 1) s += __shfl_xor(s, off, 64);
  if (lane == 0) {
    out2[row] = s * (1.25f / 512.f);
    atomicAdd(counts + idx, 1u);
  }
}

// ------------------------------------------------------------------- entropy
__global__ __launch_bounds__(256) void vq_entropy(const unsigned int* __restrict__ counts,
                                                  float* __restrict__ out4) {
  __shared__ double sd[256];
  int tid = threadIdx.x;
  double e = 0.0;
  for (int v = tid; v < V; v += 256) {
    double p = (double)counts[v] * (1.0 / (double)N);
    e += p * log(p + 1e-10);
  }
  sd[tid] = e;
  __syncthreads();
  for (int s = 128; s > 0; s >>= 1) {
    if (tid < s) sd[tid] += sd[tid + s];
    __syncthreads();
  }
  if (tid == 0) *out4 = -(float)sd[0];
}

// ---------------------------------------------------------------------------
extern "C" void kernel_launch(void* const* d_in, const int* in_sizes, int n_in,
                              void* d_out, int out_size, void* d_ws, size_t ws_size,
                              hipStream_t stream) {
  const float* zr = (const float*)d_in[0];
  const float* zi = (const float*)d_in[1];
  const float* w = (const float*)d_in[2];

  float* out = (float*)d_out;
  float* out0 = out;                       // z_q real   (N*D)
  float* out1 = out + (size_t)N * D;       // z_q imag   (N*D)
  float* out2 = out + (size_t)2 * N * D;   // loss       (N)
  float* out3 = out2 + N;                  // indices    (N, as float)
  float* out4 = out3 + N;                  // entropy    (1)

  // top-2 partials live in the z_q output region; vq_gather overwrites it later
  float* pm1 = out;                              // N*128 floats = 8 MiB
  float* pm2 = out + (size_t)N * 128;            // 8 MiB
  int* pi1 = (int*)(out + (size_t)2 * N * 128);  // 8 MiB

  char* ws = (char*)d_ws;
  unsigned short* Zh = (unsigned short*)ws;                          // 16 MiB
  unsigned short* Zl = (unsigned short*)(ws + (((size_t)16) << 20)); // 16 MiB
  unsigned short* Wh = (unsigned short*)(ws + (((size_t)32) << 20)); // 8 MiB
  unsigned short* Wl = (unsigned short*)(ws + (((size_t)40) << 20)); // 8 MiB
  char* ws2 = ws + (((size_t)48) << 20);
  double* w2d = (double*)ws2;                          // 64 KiB
  float* w2f = (float*)(ws2 + 65536);                  // 32 KiB
  unsigned int* counts = (unsigned int*)(ws2 + 98304); // 32 KiB
  int* ws_idx = (int*)(ws2 + 131072);                  // 64 KiB
  int* flaglist = (int*)(ws2 + 196608);                // 64 KiB
  int* nflag = (int*)(ws2 + 262144);                   // 4 B

  (void)hipMemsetAsync(counts, 0, V * sizeof(unsigned int), stream);
  (void)hipMemsetAsync(nflag, 0, sizeof(int), stream);

  vq_split_z<<<N * 128 / 256, 256, 0, stream>>>(zr, zi, Zh, Zl);
  vq_split_w<<<V * 128 / 256, 256, 0, stream>>>(w, Wh, Wl);
  vq_w2<<<V / 4, 256, 0, stream>>>(w, w2d, w2f);
  vq_pass1<<<(N / 128) * (V / 128), 256, 0, stream>>>(Zh, Zl, Wh, Wl, w2f, pm1, pm2, pi1);
  vq_reduce<<<N / 4, 256, 0, stream>>>(pm1, pm2, pi1, out3, ws_idx, flaglist, nflag);
  vq_fixup<<<1024, 256, 0, stream>>>(zr, zi, w, w2d, flaglist, nflag, out3, ws_idx);
  vq_gather<<<N / 4, 256, 0, stream>>>(zr, zi, w, ws_idx, out0, out1, out2, counts);
  vq_entropy<<<1, 256, 0, stream>>>(counts, out4);
}

// Round 5
// 573.064 us; speedup vs baseline: 13.1837x; 1.7998x over previous
//
#include <hip/hip_runtime.h>
#include <cmath>

typedef __bf16 bf16x8 __attribute__((ext_vector_type(8)));
typedef float f32x4 __attribute__((ext_vector_type(4)));

constexpr int N = 16384;   // rows
constexpr int D = 256;     // half feature dim
constexpr int K = 512;     // 2D
constexpr int V = 8192;    // codebook size
// split-bf16 score error: |2*(zl.wl + fp32 accum)| ~ 2.4e-4 at 6 sigma -> 16x margin
constexpr float TAU = 4e-3f;

#define GLOAD16(g, l) __builtin_amdgcn_global_load_lds(                     \
    (const __attribute__((address_space(1))) void*)(g),                    \
    (__attribute__((address_space(3))) void*)(l), 16, 0, 0)

__device__ __forceinline__ unsigned short f2bf(float x) {
  union { float f; unsigned u; } v; v.f = x;
  unsigned r = v.u + 0x7fffu + ((v.u >> 16) & 1u);  // RN-even; inputs have no NaN
  return (unsigned short)(r >> 16);
}
__device__ __forceinline__ float bf2f(unsigned short b) {
  union { unsigned u; float f; } v; v.u = ((unsigned)b) << 16; return v.f;
}

// ----------------------------------------- split z (concat real|imag) to bf16 hi/lo
__global__ __launch_bounds__(256) void vq_split_z(
    const float* __restrict__ zr, const float* __restrict__ zi,
    unsigned short* __restrict__ Zh, unsigned short* __restrict__ Zl) {
  int t = blockIdx.x * 256 + threadIdx.x;   // [0, N*128)
  int n = t >> 7, c4 = t & 127, k = c4 * 4;
  const float* src = (k < D) ? zr + (size_t)n * D + k : zi + (size_t)n * D + (k - D);
  float4 v = *(const float4*)src;
  ushort4 h, l;
  h.x = f2bf(v.x); l.x = f2bf(v.x - bf2f(h.x));
  h.y = f2bf(v.y); l.y = f2bf(v.y - bf2f(h.y));
  h.z = f2bf(v.z); l.z = f2bf(v.z - bf2f(h.z));
  h.w = f2bf(v.w); l.w = f2bf(v.w - bf2f(h.w));
  *(ushort4*)&Zh[(size_t)n * K + k] = h;
  *(ushort4*)&Zl[(size_t)n * K + k] = l;
}

// --------------------------------------------------------- split w to bf16 hi/lo
__global__ __launch_bounds__(256) void vq_split_w(
    const float* __restrict__ w,
    unsigned short* __restrict__ Wh, unsigned short* __restrict__ Wl) {
  int t = blockIdx.x * 256 + threadIdx.x;   // [0, V*128)
  int vrow = t >> 7, c4 = t & 127, k = c4 * 4;
  float4 v = *(const float4*)(w + (size_t)vrow * K + k);
  ushort4 h, l;
  h.x = f2bf(v.x); l.x = f2bf(v.x - bf2f(h.x));
  h.y = f2bf(v.y); l.y = f2bf(v.y - bf2f(h.y));
  h.z = f2bf(v.z); l.z = f2bf(v.z - bf2f(h.z));
  h.w = f2bf(v.w); l.w = f2bf(v.w - bf2f(h.w));
  *(ushort4*)&Wh[(size_t)vrow * K + k] = h;
  *(ushort4*)&Wl[(size_t)vrow * K + k] = l;
}

// ---------------------------------------------------------------- w2 = ||w||^2
__global__ __launch_bounds__(256) void vq_w2(const float* __restrict__ w,
                                             double* __restrict__ w2d,
                                             float* __restrict__ w2f) {
  int v = blockIdx.x * 4 + (threadIdx.x >> 6);
  int lane = threadIdx.x & 63;
  const float4* wr = (const float4*)(w + (size_t)v * K);
  float4 a = wr[lane];
  float4 b = wr[64 + lane];
  double s = (double)a.x * a.x + (double)a.y * a.y + (double)a.z * a.z + (double)a.w * a.w +
             (double)b.x * b.x + (double)b.y * b.y + (double)b.z * b.z + (double)b.w * b.w;
#pragma unroll
  for (int off = 1; off < 64; off <<= 1) s += __shfl_xor(s, off, 64);
  if (lane == 0) { w2d[v] = s; w2f[v] = (float)s; }
}

// ------------------- pass 1: split-bf16 MFMA GEMM + per-(row, 64-col) top-2
// 2-phase double-buffered staging (issue next tile before compute, 1 barrier/step)
// grid 8192: vt = bid & 63 (V/128), nt = bid >> 6 (N/128). 256 thr = 4 waves 2x2.
__global__ __launch_bounds__(256) void vq_pass1(
    const unsigned short* __restrict__ Zh, const unsigned short* __restrict__ Zl,
    const unsigned short* __restrict__ Wh, const unsigned short* __restrict__ Wl,
    const float* __restrict__ w2f,
    float* __restrict__ pm1, float* __restrict__ pm2, int* __restrict__ pi1) {
  // per buffer: 4 tiles of [128 rows][32 k] bf16, 8 KiB each: Ah | Al | Bh | Bl
  __shared__ __align__(16) unsigned short smem[2][16384];

  const int tid = threadIdx.x;
  const int w = tid >> 6, lane = tid & 63;
  const int wr = w >> 1, wc = w & 1;
  const int tx = lane & 15, g = lane >> 4;
  const int rsub = lane >> 2, kq = lane & 3;     // staging row-sub / k-quad
  const int vt = blockIdx.x & 63, nt = blockIdx.x >> 6;
  const int rowBase = nt * 128, colBase = vt * 128;

  f32x4 acc[4][4];
#pragma unroll
  for (int m = 0; m < 4; ++m)
#pragma unroll
    for (int n = 0; n < 4; ++n) acc[m][n] = f32x4{0.f, 0.f, 0.f, 0.f};

  const int sst = (rsub >> 1) & 3;  // stage-side swizzle (pre-swizzled global src)
  const int srd = (tx >> 1) & 3;    // read-side swizzle (same involution)

  // staging: 8 chunks of 16 rows; chunk c handled by wave c>>1, half c&1
  const int c0 = 2 * w, c1 = 2 * w + 1;
  const int grow0 = c0 * 16 + rsub, grow1 = c1 * 16 + rsub;
  const int klane = ((kq ^ sst) << 3);

#define STAGE(buf, kt)                                                        \
  do {                                                                        \
    const size_t z0 = (size_t)(rowBase + grow0) * K + (kt) + klane;           \
    const size_t w0 = (size_t)(colBase + grow0) * K + (kt) + klane;           \
    const size_t z1 = (size_t)(rowBase + grow1) * K + (kt) + klane;           \
    const size_t w1 = (size_t)(colBase + grow1) * K + (kt) + klane;           \
    GLOAD16(Zh + z0, &smem[buf][c0 * 512]);                                   \
    GLOAD16(Zl + z0, &smem[buf][4096 + c0 * 512]);                            \
    GLOAD16(Wh + w0, &smem[buf][8192 + c0 * 512]);                            \
    GLOAD16(Wl + w0, &smem[buf][12288 + c0 * 512]);                           \
    GLOAD16(Zh + z1, &smem[buf][c1 * 512]);                                   \
    GLOAD16(Zl + z1, &smem[buf][4096 + c1 * 512]);                            \
    GLOAD16(Wh + w1, &smem[buf][8192 + c1 * 512]);                            \
    GLOAD16(Wl + w1, &smem[buf][12288 + c1 * 512]);                           \
  } while (0)

  STAGE(0, 0);
  __syncthreads();  // drains vmcnt(0): buffer 0 staged & visible

  for (int t = 0; t < 16; ++t) {
    const int cur = t & 1;
    if (t < 15) STAGE(cur ^ 1, (t + 1) * 32);  // prefetch overlaps this tile's compute

    bf16x8 ah[4], al[4], bh[4], bl[4];
#pragma unroll
    for (int m = 0; m < 4; ++m) {
      const int off = (wr * 64 + m * 16 + tx) * 32 + ((g ^ srd) << 3);
      ah[m] = *(const bf16x8*)&smem[cur][off];
      al[m] = *(const bf16x8*)&smem[cur][4096 + off];
    }
#pragma unroll
    for (int n = 0; n < 4; ++n) {
      const int off = (wc * 64 + n * 16 + tx) * 32 + ((g ^ srd) << 3);
      bh[n] = *(const bf16x8*)&smem[cur][8192 + off];
      bl[n] = *(const bf16x8*)&smem[cur][12288 + off];
    }
#pragma unroll
    for (int m = 0; m < 4; ++m)
#pragma unroll
      for (int n = 0; n < 4; ++n) {
        acc[m][n] = __builtin_amdgcn_mfma_f32_16x16x32_bf16(ah[m], bh[n], acc[m][n], 0, 0, 0);
        acc[m][n] = __builtin_amdgcn_mfma_f32_16x16x32_bf16(ah[m], bl[n], acc[m][n], 0, 0, 0);
        acc[m][n] = __builtin_amdgcn_mfma_f32_16x16x32_bf16(al[m], bh[n], acc[m][n], 0, 0, 0);
      }
    __syncthreads();  // readers done with smem[cur]; prefetch (vmcnt) drained
  }
#undef STAGE

  // epilogue: scores = w2 - 2*dot, per-row top-2 over this wave's 64 cols
  float wcol[4];
#pragma unroll
  for (int n = 0; n < 4; ++n) wcol[n] = w2f[colBase + wc * 64 + n * 16 + tx];
  const int cb = vt * 2 + wc;

#pragma unroll
  for (int m = 0; m < 4; ++m) {
#pragma unroll
    for (int r = 0; r < 4; ++r) {
      float m1 = 3.4e38f, m2 = 3.4e38f;
      int i1 = 0;
#pragma unroll
      for (int n = 0; n < 4; ++n) {   // ascending v -> ties keep smallest index
        float s = fmaf(-2.0f, acc[m][n][r], wcol[n]);
        if (s < m1) { m2 = m1; m1 = s; i1 = colBase + wc * 64 + n * 16 + tx; }
        else m2 = fminf(m2, s);
      }
#pragma unroll
      for (int off = 1; off < 16; off <<= 1) {  // reduce 16 lanes sharing a row
        float om1 = __shfl_xor(m1, off, 64);
        float om2 = __shfl_xor(m2, off, 64);
        int oi = __shfl_xor(i1, off, 64);
        float nm2 = fminf(fmaxf(m1, om1), fminf(m2, om2));
        if (om1 < m1 || (om1 == m1 && oi < i1)) { m1 = om1; i1 = oi; }
        m2 = nm2;
      }
      if (tx == 0) {
        int row = rowBase + wr * 64 + m * 16 + g * 4 + r;
        size_t o = (size_t)row * 128 + cb;
        pm1[o] = m1; pm2[o] = m2; pi1[o] = i1;
      }
    }
  }
}

// ------------------- reduce 128 column-half partials per row -> argmin + flag
__global__ __launch_bounds__(256) void vq_reduce(
    const float* __restrict__ pm1, const float* __restrict__ pm2,
    const int* __restrict__ pi1,
    float* __restrict__ out_idx, int* __restrict__ ws_idx,
    int* __restrict__ flaglist, int* __restrict__ nflag) {
  int row = blockIdx.x * 4 + (threadIdx.x >> 6);
  int lane = threadIdx.x & 63;
  size_t b = (size_t)row * 128;
  float a1 = pm1[b + lane], a2 = pm2[b + lane];
  int ai = pi1[b + lane];
  float b1 = pm1[b + lane + 64], b2 = pm2[b + lane + 64];
  int bi = pi1[b + lane + 64];
  float nm2 = fminf(fmaxf(a1, b1), fminf(a2, b2));
  if (b1 < a1 || (b1 == a1 && bi < ai)) { a1 = b1; ai = bi; }
  a2 = nm2;
#pragma unroll
  for (int off = 1; off < 64; off <<= 1) {
    float o1 = __shfl_xor(a1, off, 64);
    float o2 = __shfl_xor(a2, off, 64);
    int oi = __shfl_xor(ai, off, 64);
    float n2 = fminf(fmaxf(a1, o1), fminf(a2, o2));
    if (o1 < a1 || (o1 == a1 && oi < ai)) { a1 = o1; ai = oi; }
    a2 = n2;
  }
  if (lane == 0) {
    out_idx[row] = (float)ai;
    ws_idx[row] = ai;
    if (a2 - a1 < TAU) {
      int slot = atomicAdd(nflag, 1);
      flaglist[slot] = row;
    }
  }
}

// -------- pass 2: exact fp64 rescore of CANDIDATE halves only, flagged rows
// candidates = halves with pm1_half <= m1 + TAU (superset of any exact argmin)
__global__ __launch_bounds__(256) void vq_fixup(
    const float* __restrict__ zr, const float* __restrict__ zi,
    const float* __restrict__ w, const double* __restrict__ w2d,
    const float* __restrict__ pm1,
    const int* __restrict__ flaglist, const int* __restrict__ nflag,
    float* __restrict__ out_idx, int* __restrict__ ws_idx) {
  __shared__ float zrow[K];
  __shared__ float redf[128];
  __shared__ int cand[128];
  __shared__ int ncand_s;
  __shared__ double smin[64];
  __shared__ int sidx[64];
  const int tid = threadIdx.x;
  const int nf = *nflag;
  const int g4 = tid >> 2, sub = tid & 3;

  for (int f = blockIdx.x; f < nf; f += gridDim.x) {
    const int row = flaglist[f];
    __syncthreads();  // guard LDS reuse across grid-stride rows
    if (tid == 0) ncand_s = 0;
    for (int k = tid; k < K; k += 256)
      zrow[k] = (k < D) ? zr[(size_t)row * D + k] : zi[(size_t)row * D + (k - D)];
    float h = 3.4e38f;
    if (tid < 128) { h = pm1[(size_t)row * 128 + tid]; redf[tid] = h; }
    __syncthreads();
    for (int s = 64; s > 0; s >>= 1) {  // min over the 128 half-minima
      if (tid < s) redf[tid] = fminf(redf[tid], redf[tid + s]);
      __syncthreads();
    }
    const float m1 = redf[0];
    if (tid < 128 && h <= m1 + TAU) {
      int slot = atomicAdd(&ncand_s, 1);
      cand[slot] = tid;   // order scrambled; comparator below is order-independent
    }
    __syncthreads();
    const int nc = ncand_s;

    double best = 1e300;
    int bidx = 0x7fffffff;
    for (int ci = 0; ci < nc; ++ci) {
      const int v = cand[ci] * 64 + g4;   // 64 groups x 4 threads = one half
      const float4* wr4 = (const float4*)(w + (size_t)v * K + sub * 128);
      const float4* zl4 = (const float4*)(zrow + sub * 128);
      double d0 = 0.0, d1 = 0.0;
#pragma unroll
      for (int k4 = 0; k4 < 32; k4 += 2) {
        float4 a0 = wr4[k4], b0 = zl4[k4];
        float4 a1 = wr4[k4 + 1], b1 = zl4[k4 + 1];
        d0 = fma((double)a0.x, (double)b0.x, d0); d0 = fma((double)a0.y, (double)b0.y, d0);
        d0 = fma((double)a0.z, (double)b0.z, d0); d0 = fma((double)a0.w, (double)b0.w, d0);
        d1 = fma((double)a1.x, (double)b1.x, d1); d1 = fma((double)a1.y, (double)b1.y, d1);
        d1 = fma((double)a1.z, (double)b1.z, d1); d1 = fma((double)a1.w, (double)b1.w, d1);
      }
      double dot = d0 + d1;               // deterministic 4-lane combine
      dot += __shfl_xor(dot, 1, 64);
      dot += __shfl_xor(dot, 2, 64);
      double d = w2d[v] - 2.0 * dot;
      if (sub == 0 && (d < best || (d == best && v < bidx))) { best = d; bidx = v; }
    }
    if (sub == 0) { smin[g4] = best; sidx[g4] = bidx; }
    __syncthreads();
    for (int s = 32; s > 0; s >>= 1) {
      if (tid < s) {
        if (smin[tid + s] < smin[tid] ||
            (smin[tid + s] == smin[tid] && sidx[tid + s] < sidx[tid])) {
          smin[tid] = smin[tid + s];
          sidx[tid] = sidx[tid + s];
        }
      }
      __syncthreads();
    }
    if (tid == 0) { out_idx[row] = (float)sidx[0]; ws_idx[row] = sidx[0]; }
  }
}

// ---------------- gather z_q, write outputs 0/1, loss, histogram for entropy
__global__ __launch_bounds__(256) void vq_gather(
    const float* __restrict__ zr, const float* __restrict__ zi,
    const float* __restrict__ w, const int* __restrict__ ws_idx,
    float* __restrict__ out0, float* __restrict__ out1,
    float* __restrict__ out2, unsigned int* __restrict__ counts) {
  int row = blockIdx.x * 4 + (threadIdx.x >> 6);
  int lane = threadIdx.x & 63;
  int idx = ws_idx[row];
  const float4* wr = (const float4*)(w + (size_t)idx * K);
  float4 q0 = wr[lane];
  float4 q1 = wr[64 + lane];
  float4 a = ((const float4*)(zr + (size_t)row * D))[lane];
  float4 b = ((const float4*)(zi + (size_t)row * D))[lane];
  ((float4*)(out0 + (size_t)row * D))[lane] = q0;
  ((float4*)(out1 + (size_t)row * D))[lane] = q1;

  float s = 0.f, dx;
  dx = q0.x - a.x; s = fmaf(dx, dx, s);
  dx = q0.y - a.y; s = fmaf(dx, dx, s);
  dx = q0.z - a.z; s = fmaf(dx, dx, s);
  dx = q0.w - a.w; s = fmaf(dx, dx, s);
  dx = q1.x - b.x; s = fmaf(dx, dx, s);
  dx = q1.y - b.y; s = fmaf(dx, dx, s);
  dx = q1.z - b.z; s = fmaf(dx, dx, s);
  dx = q1.w - b.w; s = fmaf(dx, dx, s);
#pragma unroll
  for (int off = 1; off < 64; off <<= 1) s += __shfl_xor(s, off, 64);
  if (lane == 0) {
    out2[row] = s * (1.25f / 512.f);
    atomicAdd(counts + idx, 1u);
  }
}

// ------------------------------------------------------------------- entropy
__global__ __launch_bounds__(256) void vq_entropy(const unsigned int* __restrict__ counts,
                                                  float* __restrict__ out4) {
  __shared__ double sd[256];
  int tid = threadIdx.x;
  double e = 0.0;
  for (int v = tid; v < V; v += 256) {
    double p = (double)counts[v] * (1.0 / (double)N);
    e += p * log(p + 1e-10);
  }
  sd[tid] = e;
  __syncthreads();
  for (int s = 128; s > 0; s >>= 1) {
    if (tid < s) sd[tid] += sd[tid + s];
    __syncthreads();
  }
  if (tid == 0) *out4 = -(float)sd[0];
}

// ---------------------------------------------------------------------------
extern "C" void kernel_launch(void* const* d_in, const int* in_sizes, int n_in,
                              void* d_out, int out_size, void* d_ws, size_t ws_size,
                              hipStream_t stream) {
  const float* zr = (const float*)d_in[0];
  const float* zi = (const float*)d_in[1];
  const float* w = (const float*)d_in[2];

  float* out = (float*)d_out;
  float* out0 = out;                       // z_q real   (N*D)
  float* out1 = out + (size_t)N * D;       // z_q imag   (N*D)
  float* out2 = out + (size_t)2 * N * D;   // loss       (N)
  float* out3 = out2 + N;                  // indices    (N, as float)
  float* out4 = out3 + N;                  // entropy    (1)

  // top-2 partials live in the z_q output region; vq_gather overwrites it later
  float* pm1 = out;                              // N*128 floats = 8 MiB
  float* pm2 = out + (size_t)N * 128;            // 8 MiB
  int* pi1 = (int*)(out + (size_t)2 * N * 128);  // 8 MiB

  char* ws = (char*)d_ws;
  unsigned short* Zh = (unsigned short*)ws;                          // 16 MiB
  unsigned short* Zl = (unsigned short*)(ws + (((size_t)16) << 20)); // 16 MiB
  unsigned short* Wh = (unsigned short*)(ws + (((size_t)32) << 20)); // 8 MiB
  unsigned short* Wl = (unsigned short*)(ws + (((size_t)40) << 20)); // 8 MiB
  char* ws2 = ws + (((size_t)48) << 20);
  double* w2d = (double*)ws2;                          // 64 KiB
  float* w2f = (float*)(ws2 + 65536);                  // 32 KiB
  unsigned int* counts = (unsigned int*)(ws2 + 98304); // 32 KiB
  int* ws_idx = (int*)(ws2 + 131072);                  // 64 KiB
  int* flaglist = (int*)(ws2 + 196608);                // 64 KiB
  int* nflag = (int*)(ws2 + 262144);                   // 4 B

  (void)hipMemsetAsync(counts, 0, V * sizeof(unsigned int), stream);
  (void)hipMemsetAsync(nflag, 0, sizeof(int), stream);

  vq_split_z<<<N * 128 / 256, 256, 0, stream>>>(zr, zi, Zh, Zl);
  vq_split_w<<<V * 128 / 256, 256, 0, stream>>>(w, Wh, Wl);
  vq_w2<<<V / 4, 256, 0, stream>>>(w, w2d, w2f);
  vq_pass1<<<(N / 128) * (V / 128), 256, 0, stream>>>(Zh, Zl, Wh, Wl, w2f, pm1, pm2, pi1);
  vq_reduce<<<N / 4, 256, 0, stream>>>(pm1, pm2, pi1, out3, ws_idx, flaglist, nflag);
  vq_fixup<<<1024, 256, 0, stream>>>(zr, zi, w, w2d, pm1, flaglist, nflag, out3, ws_idx);
  vq_gather<<<N / 4, 256, 0, stream>>>(zr, zi, w, ws_idx, out0, out1, out2, counts);
  vq_entropy<<<1, 256, 0, stream>>>(counts, out4);
}

// Round 6
// 556.866 us; speedup vs baseline: 13.5672x; 1.0291x over previous
//
#include <hip/hip_runtime.h>
#include <cmath>

typedef __bf16 bf16x8 __attribute__((ext_vector_type(8)));
typedef float f32x4 __attribute__((ext_vector_type(4)));

constexpr int N = 16384;   // rows
constexpr int D = 256;     // half feature dim
constexpr int K = 512;     // 2D
constexpr int V = 8192;    // codebook size
// split-bf16 score error: |2*(zl.wl + fp32 accum)| ~ 2.4e-4 at 6 sigma -> 16x margin
constexpr float TAU = 4e-3f;

#define GLOAD16(g, l) __builtin_amdgcn_global_load_lds(                     \
    (const __attribute__((address_space(1))) void*)(g),                    \
    (__attribute__((address_space(3))) void*)(l), 16, 0, 0)

__device__ __forceinline__ unsigned short f2bf(float x) {
  union { float f; unsigned u; } v; v.f = x;
  unsigned r = v.u + 0x7fffu + ((v.u >> 16) & 1u);  // RN-even; inputs have no NaN
  return (unsigned short)(r >> 16);
}
__device__ __forceinline__ float bf2f(unsigned short b) {
  union { unsigned u; float f; } v; v.u = ((unsigned)b) << 16; return v.f;
}

// ----------------------------------------- split z (concat real|imag) to bf16 hi/lo
__global__ __launch_bounds__(256) void vq_split_z(
    const float* __restrict__ zr, const float* __restrict__ zi,
    unsigned short* __restrict__ Zh, unsigned short* __restrict__ Zl) {
  int t = blockIdx.x * 256 + threadIdx.x;   // [0, N*128)
  int n = t >> 7, c4 = t & 127, k = c4 * 4;
  const float* src = (k < D) ? zr + (size_t)n * D + k : zi + (size_t)n * D + (k - D);
  float4 v = *(const float4*)src;
  ushort4 h, l;
  h.x = f2bf(v.x); l.x = f2bf(v.x - bf2f(h.x));
  h.y = f2bf(v.y); l.y = f2bf(v.y - bf2f(h.y));
  h.z = f2bf(v.z); l.z = f2bf(v.z - bf2f(h.z));
  h.w = f2bf(v.w); l.w = f2bf(v.w - bf2f(h.w));
  *(ushort4*)&Zh[(size_t)n * K + k] = h;
  *(ushort4*)&Zl[(size_t)n * K + k] = l;
}

// --------------------------------------------------------- split w to bf16 hi/lo
__global__ __launch_bounds__(256) void vq_split_w(
    const float* __restrict__ w,
    unsigned short* __restrict__ Wh, unsigned short* __restrict__ Wl) {
  int t = blockIdx.x * 256 + threadIdx.x;   // [0, V*128)
  int vrow = t >> 7, c4 = t & 127, k = c4 * 4;
  float4 v = *(const float4*)(w + (size_t)vrow * K + k);
  ushort4 h, l;
  h.x = f2bf(v.x); l.x = f2bf(v.x - bf2f(h.x));
  h.y = f2bf(v.y); l.y = f2bf(v.y - bf2f(h.y));
  h.z = f2bf(v.z); l.z = f2bf(v.z - bf2f(h.z));
  h.w = f2bf(v.w); l.w = f2bf(v.w - bf2f(h.w));
  *(ushort4*)&Wh[(size_t)vrow * K + k] = h;
  *(ushort4*)&Wl[(size_t)vrow * K + k] = l;
}

// ---------------------------------------------------------------- w2 = ||w||^2
__global__ __launch_bounds__(256) void vq_w2(const float* __restrict__ w,
                                             double* __restrict__ w2d,
                                             float* __restrict__ w2f) {
  int v = blockIdx.x * 4 + (threadIdx.x >> 6);
  int lane = threadIdx.x & 63;
  const float4* wr = (const float4*)(w + (size_t)v * K);
  float4 a = wr[lane];
  float4 b = wr[64 + lane];
  double s = (double)a.x * a.x + (double)a.y * a.y + (double)a.z * a.z + (double)a.w * a.w +
             (double)b.x * b.x + (double)b.y * b.y + (double)b.z * b.z + (double)b.w * b.w;
#pragma unroll
  for (int off = 1; off < 64; off <<= 1) s += __shfl_xor(s, off, 64);
  if (lane == 0) { w2d[v] = s; w2f[v] = (float)s; }
}

// ------------------- pass 1: split-bf16 MFMA GEMM + per-(row, 64-col) top-2
// 2-phase dbuf with COUNTED vmcnt + raw s_barrier: prefetch stays in flight
// across barriers (T3-min + T4). grid 8192: vt = bid & 63, nt = bid >> 6.
__global__ __launch_bounds__(256) void vq_pass1(
    const unsigned short* __restrict__ Zh, const unsigned short* __restrict__ Zl,
    const unsigned short* __restrict__ Wh, const unsigned short* __restrict__ Wl,
    const float* __restrict__ w2f,
    float* __restrict__ pm1, float* __restrict__ pm2, int* __restrict__ pi1) {
  // per buffer: 4 tiles of [128 rows][32 k] bf16, 8 KiB each: Ah | Al | Bh | Bl
  __shared__ __align__(16) unsigned short smem[2][16384];

  const int tid = threadIdx.x;
  const int w = tid >> 6, lane = tid & 63;
  const int wr = w >> 1, wc = w & 1;
  const int tx = lane & 15, g = lane >> 4;
  const int rsub = lane >> 2, kq = lane & 3;     // staging row-sub / k-quad
  const int vt = blockIdx.x & 63, nt = blockIdx.x >> 6;
  const int rowBase = nt * 128, colBase = vt * 128;

  f32x4 acc[4][4];
#pragma unroll
  for (int m = 0; m < 4; ++m)
#pragma unroll
    for (int n = 0; n < 4; ++n) acc[m][n] = f32x4{0.f, 0.f, 0.f, 0.f};

  const int sst = (rsub >> 1) & 3;  // stage-side swizzle (pre-swizzled global src)
  const int srd = (tx >> 1) & 3;    // read-side swizzle (same involution)

  // staging: 8 chunks of 16 rows; chunk c handled by wave c>>1, half c&1
  const int c0 = 2 * w, c1 = 2 * w + 1;
  const int grow0 = c0 * 16 + rsub, grow1 = c1 * 16 + rsub;
  const int klane = ((kq ^ sst) << 3);

  // hoisted per-lane global base pointers (advance by koff only in the loop)
  const size_t zo0 = (size_t)(rowBase + grow0) * K + klane;
  const size_t zo1 = (size_t)(rowBase + grow1) * K + klane;
  const size_t wo0 = (size_t)(colBase + grow0) * K + klane;
  const size_t wo1 = (size_t)(colBase + grow1) * K + klane;
  const unsigned short* zh0 = Zh + zo0;
  const unsigned short* zl0 = Zl + zo0;
  const unsigned short* wh0 = Wh + wo0;
  const unsigned short* wl0 = Wl + wo0;
  const unsigned short* zh1 = Zh + zo1;
  const unsigned short* zl1 = Zl + zo1;
  const unsigned short* wh1 = Wh + wo1;
  const unsigned short* wl1 = Wl + wo1;

#define STAGE(buf, koff)                                                      \
  do {                                                                        \
    GLOAD16(zh0 + (koff), &smem[buf][c0 * 512]);                              \
    GLOAD16(zl0 + (koff), &smem[buf][4096 + c0 * 512]);                       \
    GLOAD16(wh0 + (koff), &smem[buf][8192 + c0 * 512]);                       \
    GLOAD16(wl0 + (koff), &smem[buf][12288 + c0 * 512]);                      \
    GLOAD16(zh1 + (koff), &smem[buf][c1 * 512]);                              \
    GLOAD16(zl1 + (koff), &smem[buf][4096 + c1 * 512]);                       \
    GLOAD16(wh1 + (koff), &smem[buf][8192 + c1 * 512]);                       \
    GLOAD16(wl1 + (koff), &smem[buf][12288 + c1 * 512]);                      \
  } while (0)

  STAGE(0, 0);    // tile 0: 8 loads in flight
  STAGE(1, 32);   // tile 1: 16 in flight

  for (int t = 0; t < 16; ++t) {
    const int cur = t & 1;
    // buf[cur] complete (8 oldest); buf[cur^1]'s 8 stay in flight across barrier
    if (t < 15) asm volatile("s_waitcnt vmcnt(8)" ::: "memory");
    else        asm volatile("s_waitcnt vmcnt(0)" ::: "memory");
    __builtin_amdgcn_s_barrier();

    bf16x8 ah[4], al[4], bh[4], bl[4];
#pragma unroll
    for (int m = 0; m < 4; ++m) {
      const int off = (wr * 64 + m * 16 + tx) * 32 + ((g ^ srd) << 3);
      ah[m] = *(const bf16x8*)&smem[cur][off];
      al[m] = *(const bf16x8*)&smem[cur][4096 + off];
    }
#pragma unroll
    for (int n = 0; n < 4; ++n) {
      const int off = (wc * 64 + n * 16 + tx) * 32 + ((g ^ srd) << 3);
      bh[n] = *(const bf16x8*)&smem[cur][8192 + off];
      bl[n] = *(const bf16x8*)&smem[cur][12288 + off];
    }
    __builtin_amdgcn_s_setprio(1);
#pragma unroll
    for (int m = 0; m < 4; ++m)
#pragma unroll
      for (int n = 0; n < 4; ++n) {
        acc[m][n] = __builtin_amdgcn_mfma_f32_16x16x32_bf16(ah[m], bh[n], acc[m][n], 0, 0, 0);
        acc[m][n] = __builtin_amdgcn_mfma_f32_16x16x32_bf16(ah[m], bl[n], acc[m][n], 0, 0, 0);
        acc[m][n] = __builtin_amdgcn_mfma_f32_16x16x32_bf16(al[m], bh[n], acc[m][n], 0, 0, 0);
      }
    __builtin_amdgcn_s_setprio(0);
    // all waves' ds_reads of buf[cur] are complete here (MFMA deps force lgkm
    // waits before the barrier) -> safe to overwrite buf[cur] after it
    __builtin_amdgcn_s_barrier();
    if (t < 14) STAGE(cur, (t + 2) * 32);
  }
#undef STAGE

  // epilogue: scores = w2 - 2*dot, per-row top-2 over this wave's 64 cols
  float wcol[4];
#pragma unroll
  for (int n = 0; n < 4; ++n) wcol[n] = w2f[colBase + wc * 64 + n * 16 + tx];
  const int cb = vt * 2 + wc;

#pragma unroll
  for (int m = 0; m < 4; ++m) {
#pragma unroll
    for (int r = 0; r < 4; ++r) {
      float m1 = 3.4e38f, m2 = 3.4e38f;
      int i1 = 0;
#pragma unroll
      for (int n = 0; n < 4; ++n) {   // ascending v -> ties keep smallest index
        float s = fmaf(-2.0f, acc[m][n][r], wcol[n]);
        if (s < m1) { m2 = m1; m1 = s; i1 = colBase + wc * 64 + n * 16 + tx; }
        else m2 = fminf(m2, s);
      }
#pragma unroll
      for (int off = 1; off < 16; off <<= 1) {  // reduce 16 lanes sharing a row
        float om1 = __shfl_xor(m1, off, 64);
        float om2 = __shfl_xor(m2, off, 64);
        int oi = __shfl_xor(i1, off, 64);
        float nm2 = fminf(fmaxf(m1, om1), fminf(m2, om2));
        if (om1 < m1 || (om1 == m1 && oi < i1)) { m1 = om1; i1 = oi; }
        m2 = nm2;
      }
      if (tx == 0) {
        int row = rowBase + wr * 64 + m * 16 + g * 4 + r;
        size_t o = (size_t)row * 128 + cb;
        pm1[o] = m1; pm2[o] = m2; pi1[o] = i1;
      }
    }
  }
}

// ------------------- reduce 128 column-half partials per row -> argmin + flag
__global__ __launch_bounds__(256) void vq_reduce(
    const float* __restrict__ pm1, const float* __restrict__ pm2,
    const int* __restrict__ pi1,
    float* __restrict__ out_idx, int* __restrict__ ws_idx,
    int* __restrict__ flaglist, int* __restrict__ nflag) {
  int row = blockIdx.x * 4 + (threadIdx.x >> 6);
  int lane = threadIdx.x & 63;
  size_t b = (size_t)row * 128;
  float a1 = pm1[b + lane], a2 = pm2[b + lane];
  int ai = pi1[b + lane];
  float b1 = pm1[b + lane + 64], b2 = pm2[b + lane + 64];
  int bi = pi1[b + lane + 64];
  float nm2 = fminf(fmaxf(a1, b1), fminf(a2, b2));
  if (b1 < a1 || (b1 == a1 && bi < ai)) { a1 = b1; ai = bi; }
  a2 = nm2;
#pragma unroll
  for (int off = 1; off < 64; off <<= 1) {
    float o1 = __shfl_xor(a1, off, 64);
    float o2 = __shfl_xor(a2, off, 64);
    int oi = __shfl_xor(ai, off, 64);
    float n2 = fminf(fmaxf(a1, o1), fminf(a2, o2));
    if (o1 < a1 || (o1 == a1 && oi < ai)) { a1 = o1; ai = oi; }
    a2 = n2;
  }
  if (lane == 0) {
    out_idx[row] = (float)ai;
    ws_idx[row] = ai;
    if (a2 - a1 < TAU) {
      int slot = atomicAdd(nflag, 1);
      flaglist[slot] = row;
    }
  }
}

// -------- pass 2: exact fp64 rescore of CANDIDATE halves only, flagged rows
// candidates = halves with pm1_half <= m1 + TAU (superset of any exact argmin)
__global__ __launch_bounds__(256) void vq_fixup(
    const float* __restrict__ zr, const float* __restrict__ zi,
    const float* __restrict__ w, const double* __restrict__ w2d,
    const float* __restrict__ pm1,
    const int* __restrict__ flaglist, const int* __restrict__ nflag,
    float* __restrict__ out_idx, int* __restrict__ ws_idx) {
  __shared__ float zrow[K];
  __shared__ float redf[128];
  __shared__ int cand[128];
  __shared__ int ncand_s;
  __shared__ double smin[64];
  __shared__ int sidx[64];
  const int tid = threadIdx.x;
  const int nf = *nflag;
  const int g4 = tid >> 2, sub = tid & 3;

  for (int f = blockIdx.x; f < nf; f += gridDim.x) {
    const int row = flaglist[f];
    __syncthreads();  // guard LDS reuse across grid-stride rows
    if (tid == 0) ncand_s = 0;
    for (int k = tid; k < K; k += 256)
      zrow[k] = (k < D) ? zr[(size_t)row * D + k] : zi[(size_t)row * D + (k - D)];
    float h = 3.4e38f;
    if (tid < 128) { h = pm1[(size_t)row * 128 + tid]; redf[tid] = h; }
    __syncthreads();
    for (int s = 64; s > 0; s >>= 1) {  // min over the 128 half-minima
      if (tid < s) redf[tid] = fminf(redf[tid], redf[tid + s]);
      __syncthreads();
    }
    const float m1 = redf[0];
    if (tid < 128 && h <= m1 + TAU) {
      int slot = atomicAdd(&ncand_s, 1);
      cand[slot] = tid;   // order scrambled; comparator below is order-independent
    }
    __syncthreads();
    const int nc = ncand_s;

    double best = 1e300;
    int bidx = 0x7fffffff;
    for (int ci = 0; ci < nc; ++ci) {
      const int v = cand[ci] * 64 + g4;   // 64 groups x 4 threads = one half
      const float4* wr4 = (const float4*)(w + (size_t)v * K + sub * 128);
      const float4* zl4 = (const float4*)(zrow + sub * 128);
      double d0 = 0.0, d1 = 0.0;
#pragma unroll
      for (int k4 = 0; k4 < 32; k4 += 2) {
        float4 a0 = wr4[k4], b0 = zl4[k4];
        float4 a1 = wr4[k4 + 1], b1 = zl4[k4 + 1];
        d0 = fma((double)a0.x, (double)b0.x, d0); d0 = fma((double)a0.y, (double)b0.y, d0);
        d0 = fma((double)a0.z, (double)b0.z, d0); d0 = fma((double)a0.w, (double)b0.w, d0);
        d1 = fma((double)a1.x, (double)b1.x, d1); d1 = fma((double)a1.y, (double)b1.y, d1);
        d1 = fma((double)a1.z, (double)b1.z, d1); d1 = fma((double)a1.w, (double)b1.w, d1);
      }
      double dot = d0 + d1;               // deterministic 4-lane combine
      dot += __shfl_xor(dot, 1, 64);
      dot += __shfl_xor(dot, 2, 64);
      double d = w2d[v] - 2.0 * dot;
      if (sub == 0 && (d < best || (d == best && v < bidx))) { best = d; bidx = v; }
    }
    if (sub == 0) { smin[g4] = best; sidx[g4] = bidx; }
    __syncthreads();
    for (int s = 32; s > 0; s >>= 1) {
      if (tid < s) {
        if (smin[tid + s] < smin[tid] ||
            (smin[tid + s] == smin[tid] && sidx[tid + s] < sidx[tid])) {
          smin[tid] = smin[tid + s];
          sidx[tid] = sidx[tid + s];
        }
      }
      __syncthreads();
    }
    if (tid == 0) { out_idx[row] = (float)sidx[0]; ws_idx[row] = sidx[0]; }
  }
}

// ---------------- gather z_q, write outputs 0/1, loss, histogram for entropy
__global__ __launch_bounds__(256) void vq_gather(
    const float* __restrict__ zr, const float* __restrict__ zi,
    const float* __restrict__ w, const int* __restrict__ ws_idx,
    float* __restrict__ out0, float* __restrict__ out1,
    float* __restrict__ out2, unsigned int* __restrict__ counts) {
  int row = blockIdx.x * 4 + (threadIdx.x >> 6);
  int lane = threadIdx.x & 63;
  int idx = ws_idx[row];
  const float4* wr = (const float4*)(w + (size_t)idx * K);
  float4 q0 = wr[lane];
  float4 q1 = wr[64 + lane];
  float4 a = ((const float4*)(zr + (size_t)row * D))[lane];
  float4 b = ((const float4*)(zi + (size_t)row * D))[lane];
  ((float4*)(out0 + (size_t)row * D))[lane] = q0;
  ((float4*)(out1 + (size_t)row * D))[lane] = q1;

  float s = 0.f, dx;
  dx = q0.x - a.x; s = fmaf(dx, dx, s);
  dx = q0.y - a.y; s = fmaf(dx, dx, s);
  dx = q0.z - a.z; s = fmaf(dx, dx, s);
  dx = q0.w - a.w; s = fmaf(dx, dx, s);
  dx = q1.x - b.x; s = fmaf(dx, dx, s);
  dx = q1.y - b.y; s = fmaf(dx, dx, s);
  dx = q1.z - b.z; s = fmaf(dx, dx, s);
  dx = q1.w - b.w; s = fmaf(dx, dx, s);
#pragma unroll
  for (int off = 1; off < 64; off <<= 1) s += __shfl_xor(s, off, 64);
  if (lane == 0) {
    out2[row] = s * (1.25f / 512.f);
    atomicAdd(counts + idx, 1u);
  }
}

// ------------------------------------------------------------------- entropy
__global__ __launch_bounds__(256) void vq_entropy(const unsigned int* __restrict__ counts,
                                                  float* __restrict__ out4) {
  __shared__ double sd[256];
  int tid = threadIdx.x;
  double e = 0.0;
  for (int v = tid; v < V; v += 256) {
    double p = (double)counts[v] * (1.0 / (double)N);
    e += p * log(p + 1e-10);
  }
  sd[tid] = e;
  __syncthreads();
  for (int s = 128; s > 0; s >>= 1) {
    if (tid < s) sd[tid] += sd[tid + s];
    __syncthreads();
  }
  if (tid == 0) *out4 = -(float)sd[0];
}

// ---------------------------------------------------------------------------
extern "C" void kernel_launch(void* const* d_in, const int* in_sizes, int n_in,
                              void* d_out, int out_size, void* d_ws, size_t ws_size,
                              hipStream_t stream) {
  const float* zr = (const float*)d_in[0];
  const float* zi = (const float*)d_in[1];
  const float* w = (const float*)d_in[2];

  float* out = (float*)d_out;
  float* out0 = out;                       // z_q real   (N*D)
  float* out1 = out + (size_t)N * D;       // z_q imag   (N*D)
  float* out2 = out + (size_t)2 * N * D;   // loss       (N)
  float* out3 = out2 + N;                  // indices    (N, as float)
  float* out4 = out3 + N;                  // entropy    (1)

  // top-2 partials live in the z_q output region; vq_gather overwrites it later
  float* pm1 = out;                              // N*128 floats = 8 MiB
  float* pm2 = out + (size_t)N * 128;            // 8 MiB
  int* pi1 = (int*)(out + (size_t)2 * N * 128);  // 8 MiB

  char* ws = (char*)d_ws;
  unsigned short* Zh = (unsigned short*)ws;                          // 16 MiB
  unsigned short* Zl = (unsigned short*)(ws + (((size_t)16) << 20)); // 16 MiB
  unsigned short* Wh = (unsigned short*)(ws + (((size_t)32) << 20)); // 8 MiB
  unsigned short* Wl = (unsigned short*)(ws + (((size_t)40) << 20)); // 8 MiB
  char* ws2 = ws + (((size_t)48) << 20);
  double* w2d = (double*)ws2;                          // 64 KiB
  float* w2f = (float*)(ws2 + 65536);                  // 32 KiB
  unsigned int* counts = (unsigned int*)(ws2 + 98304); // 32 KiB
  int* ws_idx = (int*)(ws2 + 131072);                  // 64 KiB
  int* flaglist = (int*)(ws2 + 196608);                // 64 KiB
  int* nflag = (int*)(ws2 + 262144);                   // 4 B

  (void)hipMemsetAsync(counts, 0, V * sizeof(unsigned int), stream);
  (void)hipMemsetAsync(nflag, 0, sizeof(int), stream);

  vq_split_z<<<N * 128 / 256, 256, 0, stream>>>(zr, zi, Zh, Zl);
  vq_split_w<<<V * 128 / 256, 256, 0, stream>>>(w, Wh, Wl);
  vq_w2<<<V / 4, 256, 0, stream>>>(w, w2d, w2f);
  vq_pass1<<<(N / 128) * (V / 128), 256, 0, stream>>>(Zh, Zl, Wh, Wl, w2f, pm1, pm2, pi1);
  vq_reduce<<<N / 4, 256, 0, stream>>>(pm1, pm2, pi1, out3, ws_idx, flaglist, nflag);
  vq_fixup<<<1024, 256, 0, stream>>>(zr, zi, w, w2d, pm1, flaglist, nflag, out3, ws_idx);
  vq_gather<<<N / 4, 256, 0, stream>>>(zr, zi, w, ws_idx, out0, out1, out2, counts);
  vq_entropy<<<1, 256, 0, stream>>>(counts, out4);
}

// Round 7
// 382.344 us; speedup vs baseline: 19.7600x; 1.4565x over previous
//
#include <hip/hip_runtime.h>
#include <cmath>

typedef _Float16 half8 __attribute__((ext_vector_type(8)));
typedef float f32x4 __attribute__((ext_vector_type(4)));

constexpr int N = 16384;   // rows
constexpr int D = 256;     // half feature dim
constexpr int K = 512;     // 2D
constexpr int V = 8192;    // codebook size
// fp16 scoring: provable score error bound ~0.02 (2^-11*||z||*||w||*4 + denorm
// slack); TAU >= 2B keeps the fixup set a superset of the exact argmin.
constexpr float TAU = 0.05f;

#define GLOAD16(g, l) __builtin_amdgcn_global_load_lds(                     \
    (const __attribute__((address_space(1))) void*)(g),                    \
    (__attribute__((address_space(3))) void*)(l), 16, 0, 0)

// --------------------------- convert z (concat real|imag) to fp16 [N][K]
__global__ __launch_bounds__(256) void vq_cvt_z(
    const float* __restrict__ zr, const float* __restrict__ zi,
    _Float16* __restrict__ Zf) {
  int t = blockIdx.x * 256 + threadIdx.x;   // [0, N*64)
  int n = t >> 6, c8 = t & 63, k = c8 * 8;
  const float* src = (k < D) ? zr + (size_t)n * D + k : zi + (size_t)n * D + (k - D);
  float4 a = *(const float4*)src;
  float4 b = *(const float4*)(src + 4);
  half8 h;
  h[0] = (_Float16)a.x; h[1] = (_Float16)a.y; h[2] = (_Float16)a.z; h[3] = (_Float16)a.w;
  h[4] = (_Float16)b.x; h[5] = (_Float16)b.y; h[6] = (_Float16)b.z; h[7] = (_Float16)b.w;
  *(half8*)&Zf[(size_t)n * K + k] = h;
}

// ------------------------------------------------------ convert w to fp16
__global__ __launch_bounds__(256) void vq_cvt_w(
    const float* __restrict__ w, _Float16* __restrict__ Wf) {
  int t = blockIdx.x * 256 + threadIdx.x;   // [0, V*64)
  int vrow = t >> 6, c8 = t & 63, k = c8 * 8;
  const float* src = w + (size_t)vrow * K + k;
  float4 a = *(const float4*)src;
  float4 b = *(const float4*)(src + 4);
  half8 h;
  h[0] = (_Float16)a.x; h[1] = (_Float16)a.y; h[2] = (_Float16)a.z; h[3] = (_Float16)a.w;
  h[4] = (_Float16)b.x; h[5] = (_Float16)b.y; h[6] = (_Float16)b.z; h[7] = (_Float16)b.w;
  *(half8*)&Wf[(size_t)vrow * K + k] = h;
}

// ---------------------------------------------------------------- w2 = ||w||^2
__global__ __launch_bounds__(256) void vq_w2(const float* __restrict__ w,
                                             double* __restrict__ w2d,
                                             float* __restrict__ w2f) {
  int v = blockIdx.x * 4 + (threadIdx.x >> 6);
  int lane = threadIdx.x & 63;
  const float4* wr = (const float4*)(w + (size_t)v * K);
  float4 a = wr[lane];
  float4 b = wr[64 + lane];
  double s = (double)a.x * a.x + (double)a.y * a.y + (double)a.z * a.z + (double)a.w * a.w +
             (double)b.x * b.x + (double)b.y * b.y + (double)b.z * b.z + (double)b.w * b.w;
#pragma unroll
  for (int off = 1; off < 64; off <<= 1) s += __shfl_xor(s, off, 64);
  if (lane == 0) { w2d[v] = s; w2f[v] = (float)s; }
}

// -------------------- pass 1: fp16 MFMA GEMM + per-(row, 64-col) top-2
// 2-phase dbuf, counted vmcnt + raw s_barrier (verified R5/R6 structure).
// grid 8192: vt = bid & 63 (V/128), nt = bid >> 6 (N/128). 256 thr = 4 waves 2x2.
__global__ __launch_bounds__(256) void vq_pass1(
    const _Float16* __restrict__ Zf, const _Float16* __restrict__ Wf,
    const float* __restrict__ w2f,
    float* __restrict__ pm1, float* __restrict__ pm2, int* __restrict__ pi1) {
  // per buffer: Z tile [128][32] + W tile [128][32] fp16 = 16 KiB
  __shared__ __align__(16) unsigned short smem[2][8192];

  const int tid = threadIdx.x;
  const int w = tid >> 6, lane = tid & 63;
  const int wr = w >> 1, wc = w & 1;
  const int tx = lane & 15, g = lane >> 4;
  const int rsub = lane >> 2, kq = lane & 3;     // staging row-sub / k-quad
  const int vt = blockIdx.x & 63, nt = blockIdx.x >> 6;
  const int rowBase = nt * 128, colBase = vt * 128;

  f32x4 acc[4][4];
#pragma unroll
  for (int m = 0; m < 4; ++m)
#pragma unroll
    for (int n = 0; n < 4; ++n) acc[m][n] = f32x4{0.f, 0.f, 0.f, 0.f};

  const int sst = (rsub >> 1) & 3;  // stage-side swizzle (pre-swizzled global src)
  const int srd = (tx >> 1) & 3;    // read-side swizzle (same involution)

  // staging: 8 chunks of 16 rows; chunk c handled by wave c>>1, half c&1
  const int c0 = 2 * w, c1 = 2 * w + 1;
  const int grow0 = c0 * 16 + rsub, grow1 = c1 * 16 + rsub;
  const int klane = ((kq ^ sst) << 3);

  const _Float16* z0 = Zf + (size_t)(rowBase + grow0) * K + klane;
  const _Float16* z1 = Zf + (size_t)(rowBase + grow1) * K + klane;
  const _Float16* w0 = Wf + (size_t)(colBase + grow0) * K + klane;
  const _Float16* w1 = Wf + (size_t)(colBase + grow1) * K + klane;

#define STAGE(buf, koff)                                                      \
  do {                                                                        \
    GLOAD16(z0 + (koff), &smem[buf][c0 * 512]);                               \
    GLOAD16(w0 + (koff), &smem[buf][4096 + c0 * 512]);                        \
    GLOAD16(z1 + (koff), &smem[buf][c1 * 512]);                               \
    GLOAD16(w1 + (koff), &smem[buf][4096 + c1 * 512]);                        \
  } while (0)

  STAGE(0, 0);    // tile 0: 4 loads in flight
  STAGE(1, 32);   // tile 1: 8 in flight

  for (int t = 0; t < 16; ++t) {
    const int cur = t & 1;
    // buf[cur] complete (4 oldest); buf[cur^1]'s 4 stay in flight across barrier
    if (t < 15) asm volatile("s_waitcnt vmcnt(4)" ::: "memory");
    else        asm volatile("s_waitcnt vmcnt(0)" ::: "memory");
    __builtin_amdgcn_s_barrier();

    half8 a[4], b[4];
#pragma unroll
    for (int m = 0; m < 4; ++m) {
      const int off = (wr * 64 + m * 16 + tx) * 32 + ((g ^ srd) << 3);
      a[m] = *(const half8*)&smem[cur][off];
    }
#pragma unroll
    for (int n = 0; n < 4; ++n) {
      const int off = (wc * 64 + n * 16 + tx) * 32 + ((g ^ srd) << 3);
      b[n] = *(const half8*)&smem[cur][4096 + off];
    }
    __builtin_amdgcn_s_setprio(1);
#pragma unroll
    for (int m = 0; m < 4; ++m)
#pragma unroll
      for (int n = 0; n < 4; ++n)
        acc[m][n] = __builtin_amdgcn_mfma_f32_16x16x32_f16(a[m], b[n], acc[m][n], 0, 0, 0);
    __builtin_amdgcn_s_setprio(0);
    // all waves' ds_reads of buf[cur] complete before their barrier arrival
    // (MFMA data deps force lgkm waits) -> safe to overwrite buf[cur] after it
    __builtin_amdgcn_s_barrier();
    if (t < 14) STAGE(cur, (t + 2) * 32);
  }
#undef STAGE

  // epilogue: scores = w2 - 2*dot, per-row top-2 over this wave's 64 cols
  float wcol[4];
#pragma unroll
  for (int n = 0; n < 4; ++n) wcol[n] = w2f[colBase + wc * 64 + n * 16 + tx];
  const int cb = vt * 2 + wc;

#pragma unroll
  for (int m = 0; m < 4; ++m) {
#pragma unroll
    for (int r = 0; r < 4; ++r) {
      float m1 = 3.4e38f, m2 = 3.4e38f;
      int i1 = 0;
#pragma unroll
      for (int n = 0; n < 4; ++n) {   // ascending v -> ties keep smallest index
        float s = fmaf(-2.0f, acc[m][n][r], wcol[n]);
        if (s < m1) { m2 = m1; m1 = s; i1 = colBase + wc * 64 + n * 16 + tx; }
        else m2 = fminf(m2, s);
      }
#pragma unroll
      for (int off = 1; off < 16; off <<= 1) {  // reduce 16 lanes sharing a row
        float om1 = __shfl_xor(m1, off, 64);
        float om2 = __shfl_xor(m2, off, 64);
        int oi = __shfl_xor(i1, off, 64);
        float nm2 = fminf(fmaxf(m1, om1), fminf(m2, om2));
        if (om1 < m1 || (om1 == m1 && oi < i1)) { m1 = om1; i1 = oi; }
        m2 = nm2;
      }
      if (tx == 0) {
        int row = rowBase + wr * 64 + m * 16 + g * 4 + r;
        size_t o = (size_t)row * 128 + cb;
        pm1[o] = m1; pm2[o] = m2; pi1[o] = i1;
      }
    }
  }
}

// ------------------- reduce 128 column-half partials per row -> argmin + flag
__global__ __launch_bounds__(256) void vq_reduce(
    const float* __restrict__ pm1, const float* __restrict__ pm2,
    const int* __restrict__ pi1,
    float* __restrict__ out_idx, int* __restrict__ ws_idx,
    int* __restrict__ flaglist, int* __restrict__ nflag) {
  int row = blockIdx.x * 4 + (threadIdx.x >> 6);
  int lane = threadIdx.x & 63;
  size_t b = (size_t)row * 128;
  float a1 = pm1[b + lane], a2 = pm2[b + lane];
  int ai = pi1[b + lane];
  float b1 = pm1[b + lane + 64], b2 = pm2[b + lane + 64];
  int bi = pi1[b + lane + 64];
  float nm2 = fminf(fmaxf(a1, b1), fminf(a2, b2));
  if (b1 < a1 || (b1 == a1 && bi < ai)) { a1 = b1; ai = bi; }
  a2 = nm2;
#pragma unroll
  for (int off = 1; off < 64; off <<= 1) {
    float o1 = __shfl_xor(a1, off, 64);
    float o2 = __shfl_xor(a2, off, 64);
    int oi = __shfl_xor(ai, off, 64);
    float n2 = fminf(fmaxf(a1, o1), fminf(a2, o2));
    if (o1 < a1 || (o1 == a1 && oi < ai)) { a1 = o1; ai = oi; }
    a2 = n2;
  }
  if (lane == 0) {
    out_idx[row] = (float)ai;
    ws_idx[row] = ai;
    if (a2 - a1 < TAU) {
      int slot = atomicAdd(nflag, 1);
      flaglist[slot] = row;
    }
  }
}

// -------- pass 2: exact fp64 rescore of CANDIDATE halves only, flagged rows
// candidates = halves with pm1_half <= m1 + TAU (superset of any exact argmin)
__global__ __launch_bounds__(256) void vq_fixup(
    const float* __restrict__ zr, const float* __restrict__ zi,
    const float* __restrict__ w, const double* __restrict__ w2d,
    const float* __restrict__ pm1,
    const int* __restrict__ flaglist, const int* __restrict__ nflag,
    float* __restrict__ out_idx, int* __restrict__ ws_idx) {
  __shared__ float zrow[K];
  __shared__ float redf[128];
  __shared__ int cand[128];
  __shared__ int ncand_s;
  __shared__ double smin[64];
  __shared__ int sidx[64];
  const int tid = threadIdx.x;
  const int nf = *nflag;
  const int g4 = tid >> 2, sub = tid & 3;

  for (int f = blockIdx.x; f < nf; f += gridDim.x) {
    const int row = flaglist[f];
    __syncthreads();  // guard LDS reuse across grid-stride rows
    if (tid == 0) ncand_s = 0;
    for (int k = tid; k < K; k += 256)
      zrow[k] = (k < D) ? zr[(size_t)row * D + k] : zi[(size_t)row * D + (k - D)];
    float h = 3.4e38f;
    if (tid < 128) { h = pm1[(size_t)row * 128 + tid]; redf[tid] = h; }
    __syncthreads();
    for (int s = 64; s > 0; s >>= 1) {  // min over the 128 half-minima
      if (tid < s) redf[tid] = fminf(redf[tid], redf[tid + s]);
      __syncthreads();
    }
    const float m1 = redf[0];
    if (tid < 128 && h <= m1 + TAU) {
      int slot = atomicAdd(&ncand_s, 1);
      cand[slot] = tid;   // order scrambled; comparator below is order-independent
    }
    __syncthreads();
    const int nc = ncand_s;

    double best = 1e300;
    int bidx = 0x7fffffff;
    for (int ci = 0; ci < nc; ++ci) {
      const int v = cand[ci] * 64 + g4;   // 64 groups x 4 threads = one half
      const float4* wr4 = (const float4*)(w + (size_t)v * K + sub * 128);
      const float4* zl4 = (const float4*)(zrow + sub * 128);
      double d0 = 0.0, d1 = 0.0;
#pragma unroll
      for (int k4 = 0; k4 < 32; k4 += 2) {
        float4 a0 = wr4[k4], b0 = zl4[k4];
        float4 a1 = wr4[k4 + 1], b1 = zl4[k4 + 1];
        d0 = fma((double)a0.x, (double)b0.x, d0); d0 = fma((double)a0.y, (double)b0.y, d0);
        d0 = fma((double)a0.z, (double)b0.z, d0); d0 = fma((double)a0.w, (double)b0.w, d0);
        d1 = fma((double)a1.x, (double)b1.x, d1); d1 = fma((double)a1.y, (double)b1.y, d1);
        d1 = fma((double)a1.z, (double)b1.z, d1); d1 = fma((double)a1.w, (double)b1.w, d1);
      }
      double dot = d0 + d1;               // deterministic 4-lane combine
      dot += __shfl_xor(dot, 1, 64);
      dot += __shfl_xor(dot, 2, 64);
      double d = w2d[v] - 2.0 * dot;
      if (sub == 0 && (d < best || (d == best && v < bidx))) { best = d; bidx = v; }
    }
    if (sub == 0) { smin[g4] = best; sidx[g4] = bidx; }
    __syncthreads();
    for (int s = 32; s > 0; s >>= 1) {
      if (tid < s) {
        if (smin[tid + s] < smin[tid] ||
            (smin[tid + s] == smin[tid] && sidx[tid + s] < sidx[tid])) {
          smin[tid] = smin[tid + s];
          sidx[tid] = sidx[tid + s];
        }
      }
      __syncthreads();
    }
    if (tid == 0) { out_idx[row] = (float)sidx[0]; ws_idx[row] = sidx[0]; }
  }
}

// ---------------- gather z_q, write outputs 0/1, loss, histogram for entropy
__global__ __launch_bounds__(256) void vq_gather(
    const float* __restrict__ zr, const float* __restrict__ zi,
    const float* __restrict__ w, const int* __restrict__ ws_idx,
    float* __restrict__ out0, float* __restrict__ out1,
    float* __restrict__ out2, unsigned int* __restrict__ counts) {
  int row = blockIdx.x * 4 + (threadIdx.x >> 6);
  int lane = threadIdx.x & 63;
  int idx = ws_idx[row];
  const float4* wr = (const float4*)(w + (size_t)idx * K);
  float4 q0 = wr[lane];
  float4 q1 = wr[64 + lane];
  float4 a = ((const float4*)(zr + (size_t)row * D))[lane];
  float4 b = ((const float4*)(zi + (size_t)row * D))[lane];
  ((float4*)(out0 + (size_t)row * D))[lane] = q0;
  ((float4*)(out1 + (size_t)row * D))[lane] = q1;

  float s = 0.f, dx;
  dx = q0.x - a.x; s = fmaf(dx, dx, s);
  dx = q0.y - a.y; s = fmaf(dx, dx, s);
  dx = q0.z - a.z; s = fmaf(dx, dx, s);
  dx = q0.w - a.w; s = fmaf(dx, dx, s);
  dx = q1.x - b.x; s = fmaf(dx, dx, s);
  dx = q1.y - b.y; s = fmaf(dx, dx, s);
  dx = q1.z - b.z; s = fmaf(dx, dx, s);
  dx = q1.w - b.w; s = fmaf(dx, dx, s);
#pragma unroll
  for (int off = 1; off < 64; off <<= 1) s += __shfl_xor(s, off, 64);
  if (lane == 0) {
    out2[row] = s * (1.25f / 512.f);
    atomicAdd(counts + idx, 1u);
  }
}

// ------------------------------------------------------------------- entropy
__global__ __launch_bounds__(256) void vq_entropy(const unsigned int* __restrict__ counts,
                                                  float* __restrict__ out4) {
  __shared__ double sd[256];
  int tid = threadIdx.x;
  double e = 0.0;
  for (int v = tid; v < V; v += 256) {
    double p = (double)counts[v] * (1.0 / (double)N);
    e += p * log(p + 1e-10);
  }
  sd[tid] = e;
  __syncthreads();
  for (int s = 128; s > 0; s >>= 1) {
    if (tid < s) sd[tid] += sd[tid + s];
    __syncthreads();
  }
  if (tid == 0) *out4 = -(float)sd[0];
}

// ---------------------------------------------------------------------------
extern "C" void kernel_launch(void* const* d_in, const int* in_sizes, int n_in,
                              void* d_out, int out_size, void* d_ws, size_t ws_size,
                              hipStream_t stream) {
  const float* zr = (const float*)d_in[0];
  const float* zi = (const float*)d_in[1];
  const float* w = (const float*)d_in[2];

  float* out = (float*)d_out;
  float* out0 = out;                       // z_q real   (N*D)
  float* out1 = out + (size_t)N * D;       // z_q imag   (N*D)
  float* out2 = out + (size_t)2 * N * D;   // loss       (N)
  float* out3 = out2 + N;                  // indices    (N, as float)
  float* out4 = out3 + N;                  // entropy    (1)

  // top-2 partials live in the z_q output region; vq_gather overwrites it later
  float* pm1 = out;                              // N*128 floats = 8 MiB
  float* pm2 = out + (size_t)N * 128;            // 8 MiB
  int* pi1 = (int*)(out + (size_t)2 * N * 128);  // 8 MiB

  char* ws = (char*)d_ws;
  _Float16* Zf = (_Float16*)ws;                           // 16 MiB
  _Float16* Wf = (_Float16*)(ws + (((size_t)16) << 20));  // 8 MiB
  char* ws2 = ws + (((size_t)24) << 20);
  double* w2d = (double*)ws2;                          // 64 KiB
  float* w2f = (float*)(ws2 + 65536);                  // 32 KiB
  unsigned int* counts = (unsigned int*)(ws2 + 98304); // 32 KiB
  int* ws_idx = (int*)(ws2 + 131072);                  // 64 KiB
  int* flaglist = (int*)(ws2 + 196608);                // 64 KiB
  int* nflag = (int*)(ws2 + 262144);                   // 4 B

  (void)hipMemsetAsync(counts, 0, V * sizeof(unsigned int), stream);
  (void)hipMemsetAsync(nflag, 0, sizeof(int), stream);

  vq_cvt_z<<<N * 64 / 256, 256, 0, stream>>>(zr, zi, Zf);
  vq_cvt_w<<<V * 64 / 256, 256, 0, stream>>>(w, Wf);
  vq_w2<<<V / 4, 256, 0, stream>>>(w, w2d, w2f);
  vq_pass1<<<(N / 128) * (V / 128), 256, 0, stream>>>(Zf, Wf, w2f, pm1, pm2, pi1);
  vq_reduce<<<N / 4, 256, 0, stream>>>(pm1, pm2, pi1, out3, ws_idx, flaglist, nflag);
  vq_fixup<<<2048, 256, 0, stream>>>(zr, zi, w, w2d, pm1, flaglist, nflag, out3, ws_idx);
  vq_gather<<<N / 4, 256, 0, stream>>>(zr, zi, w, ws_idx, out0, out1, out2, counts);
  vq_entropy<<<1, 256, 0, stream>>>(counts, out4);
}

// Round 8
// 379.363 us; speedup vs baseline: 19.9152x; 1.0079x over previous
//
#include <hip/hip_runtime.h>
#include <cmath>

typedef _Float16 half8 __attribute__((ext_vector_type(8)));
typedef float f32x4 __attribute__((ext_vector_type(4)));

constexpr int N = 16384;   // rows
constexpr int D = 256;     // half feature dim
constexpr int K = 512;     // 2D
constexpr int V = 8192;    // codebook size
// fp16 scoring: provable score error bound ~0.02 (2^-11*||z||*||w||*4 + denorm
// slack); TAU >= 2B keeps the fixup set a superset of the exact argmin.
constexpr float TAU = 0.05f;

#define GLOAD16(g, l) __builtin_amdgcn_global_load_lds(                     \
    (const __attribute__((address_space(1))) void*)(g),                    \
    (__attribute__((address_space(3))) void*)(l), 16, 0, 0)

// --------------------------- convert z (concat real|imag) to fp16 [N][K]
__global__ __launch_bounds__(256) void vq_cvt_z(
    const float* __restrict__ zr, const float* __restrict__ zi,
    _Float16* __restrict__ Zf) {
  int t = blockIdx.x * 256 + threadIdx.x;   // [0, N*64)
  int n = t >> 6, c8 = t & 63, k = c8 * 8;
  const float* src = (k < D) ? zr + (size_t)n * D + k : zi + (size_t)n * D + (k - D);
  float4 a = *(const float4*)src;
  float4 b = *(const float4*)(src + 4);
  half8 h;
  h[0] = (_Float16)a.x; h[1] = (_Float16)a.y; h[2] = (_Float16)a.z; h[3] = (_Float16)a.w;
  h[4] = (_Float16)b.x; h[5] = (_Float16)b.y; h[6] = (_Float16)b.z; h[7] = (_Float16)b.w;
  *(half8*)&Zf[(size_t)n * K + k] = h;
}

// ------------------------------------------------------ convert w to fp16
__global__ __launch_bounds__(256) void vq_cvt_w(
    const float* __restrict__ w, _Float16* __restrict__ Wf) {
  int t = blockIdx.x * 256 + threadIdx.x;   // [0, V*64)
  int vrow = t >> 6, c8 = t & 63, k = c8 * 8;
  const float* src = w + (size_t)vrow * K + k;
  float4 a = *(const float4*)src;
  float4 b = *(const float4*)(src + 4);
  half8 h;
  h[0] = (_Float16)a.x; h[1] = (_Float16)a.y; h[2] = (_Float16)a.z; h[3] = (_Float16)a.w;
  h[4] = (_Float16)b.x; h[5] = (_Float16)b.y; h[6] = (_Float16)b.z; h[7] = (_Float16)b.w;
  *(half8*)&Wf[(size_t)vrow * K + k] = h;
}

// ---------------------------------------------------------------- w2 = ||w||^2
__global__ __launch_bounds__(256) void vq_w2(const float* __restrict__ w,
                                             double* __restrict__ w2d,
                                             float* __restrict__ w2f) {
  int v = blockIdx.x * 4 + (threadIdx.x >> 6);
  int lane = threadIdx.x & 63;
  const float4* wr = (const float4*)(w + (size_t)v * K);
  float4 a = wr[lane];
  float4 b = wr[64 + lane];
  double s = (double)a.x * a.x + (double)a.y * a.y + (double)a.z * a.z + (double)a.w * a.w +
             (double)b.x * b.x + (double)b.y * b.y + (double)b.z * b.z + (double)b.w * b.w;
#pragma unroll
  for (int off = 1; off < 64; off <<= 1) s += __shfl_xor(s, off, 64);
  if (lane == 0) { w2d[v] = s; w2f[v] = (float)s; }
}

// -------------------- pass 1: fp16 MFMA GEMM + per-(row, 64-col) top-2
// 3-buffer LDS rotation, depth-2 prefetch, counted vmcnt + raw s_barrier.
// grid 8192: vt = bid & 63 (V/128), nt = bid >> 6 (N/128). 256 thr = 4 waves 2x2.
__global__ __launch_bounds__(256) void vq_pass1(
    const _Float16* __restrict__ Zf, const _Float16* __restrict__ Wf,
    const float* __restrict__ w2f,
    float* __restrict__ pm1, float* __restrict__ pm2, int* __restrict__ pi1) {
  // per buffer: Z tile [128][32] + W tile [128][32] fp16 = 16 KiB; 3 bufs = 48 KiB
  __shared__ __align__(16) unsigned short smem[3][8192];

  const int tid = threadIdx.x;
  const int w = tid >> 6, lane = tid & 63;
  const int wr = w >> 1, wc = w & 1;
  const int tx = lane & 15, g = lane >> 4;
  const int rsub = lane >> 2, kq = lane & 3;     // staging row-sub / k-quad
  const int vt = blockIdx.x & 63, nt = blockIdx.x >> 6;
  const int rowBase = nt * 128, colBase = vt * 128;

  f32x4 acc[4][4];
#pragma unroll
  for (int m = 0; m < 4; ++m)
#pragma unroll
    for (int n = 0; n < 4; ++n) acc[m][n] = f32x4{0.f, 0.f, 0.f, 0.f};

  const int sst = (rsub >> 1) & 3;  // stage-side swizzle (pre-swizzled global src)
  const int srd = (tx >> 1) & 3;    // read-side swizzle (same involution)

  // staging: 8 chunks of 16 rows; chunk c handled by wave c>>1, half c&1
  const int c0 = 2 * w, c1 = 2 * w + 1;
  const int grow0 = c0 * 16 + rsub, grow1 = c1 * 16 + rsub;
  const int klane = ((kq ^ sst) << 3);

  const _Float16* z0 = Zf + (size_t)(rowBase + grow0) * K + klane;
  const _Float16* z1 = Zf + (size_t)(rowBase + grow1) * K + klane;
  const _Float16* w0 = Wf + (size_t)(colBase + grow0) * K + klane;
  const _Float16* w1 = Wf + (size_t)(colBase + grow1) * K + klane;

#define STAGE(buf, koff)                                                      \
  do {                                                                        \
    GLOAD16(z0 + (koff), &smem[buf][c0 * 512]);                               \
    GLOAD16(w0 + (koff), &smem[buf][4096 + c0 * 512]);                        \
    GLOAD16(z1 + (koff), &smem[buf][c1 * 512]);                               \
    GLOAD16(w1 + (koff), &smem[buf][4096 + c1 * 512]);                        \
  } while (0)

  STAGE(0, 0);     // tile 0:  4 loads in flight
  STAGE(1, 32);    // tile 1:  8 in flight
  STAGE(2, 64);    // tile 2: 12 in flight

#pragma unroll
  for (int t = 0; t < 16; ++t) {
    const int cur = t % 3;
    // complete only the oldest 4 loads (tile t); keep up to 8 in flight
    if (t < 14)      asm volatile("s_waitcnt vmcnt(8)" ::: "memory");
    else if (t == 14) asm volatile("s_waitcnt vmcnt(4)" ::: "memory");
    else             asm volatile("s_waitcnt vmcnt(0)" ::: "memory");
    __builtin_amdgcn_s_barrier();  // all waves' tile-t loads now visible

    half8 a[4], b[4];
#pragma unroll
    for (int m = 0; m < 4; ++m) {
      const int off = (wr * 64 + m * 16 + tx) * 32 + ((g ^ srd) << 3);
      a[m] = *(const half8*)&smem[cur][off];
    }
#pragma unroll
    for (int n = 0; n < 4; ++n) {
      const int off = (wc * 64 + n * 16 + tx) * 32 + ((g ^ srd) << 3);
      b[n] = *(const half8*)&smem[cur][4096 + off];
    }
    __builtin_amdgcn_s_setprio(1);
#pragma unroll
    for (int m = 0; m < 4; ++m)
#pragma unroll
      for (int n = 0; n < 4; ++n)
        acc[m][n] = __builtin_amdgcn_mfma_f32_16x16x32_f16(a[m], b[n], acc[m][n], 0, 0, 0);
    __builtin_amdgcn_s_setprio(0);
    // all waves' ds_reads of buf[cur] complete before their barrier arrival
    // (MFMA data deps force lgkm waits) -> safe to re-stage buf[cur] after it
    __builtin_amdgcn_s_barrier();
    if (t < 13) STAGE(cur, (t + 3) * 32);
  }
#undef STAGE

  // epilogue: scores = w2 - 2*dot, per-row top-2 over this wave's 64 cols
  float wcol[4];
#pragma unroll
  for (int n = 0; n < 4; ++n) wcol[n] = w2f[colBase + wc * 64 + n * 16 + tx];
  const int cb = vt * 2 + wc;

#pragma unroll
  for (int m = 0; m < 4; ++m) {
#pragma unroll
    for (int r = 0; r < 4; ++r) {
      float m1 = 3.4e38f, m2 = 3.4e38f;
      int i1 = 0;
#pragma unroll
      for (int n = 0; n < 4; ++n) {   // ascending v -> ties keep smallest index
        float s = fmaf(-2.0f, acc[m][n][r], wcol[n]);
        if (s < m1) { m2 = m1; m1 = s; i1 = colBase + wc * 64 + n * 16 + tx; }
        else m2 = fminf(m2, s);
      }
#pragma unroll
      for (int off = 1; off < 16; off <<= 1) {  // reduce 16 lanes sharing a row
        float om1 = __shfl_xor(m1, off, 64);
        float om2 = __shfl_xor(m2, off, 64);
        int oi = __shfl_xor(i1, off, 64);
        float nm2 = fminf(fmaxf(m1, om1), fminf(m2, om2));
        if (om1 < m1 || (om1 == m1 && oi < i1)) { m1 = om1; i1 = oi; }
        m2 = nm2;
      }
      if (tx == 0) {
        int row = rowBase + wr * 64 + m * 16 + g * 4 + r;
        size_t o = (size_t)row * 128 + cb;
        pm1[o] = m1; pm2[o] = m2; pi1[o] = i1;
      }
    }
  }
}

// ------------------- reduce 128 column-half partials per row -> argmin + flag
__global__ __launch_bounds__(256) void vq_reduce(
    const float* __restrict__ pm1, const float* __restrict__ pm2,
    const int* __restrict__ pi1,
    float* __restrict__ out_idx, int* __restrict__ ws_idx,
    int* __restrict__ flaglist, int* __restrict__ nflag) {
  int row = blockIdx.x * 4 + (threadIdx.x >> 6);
  int lane = threadIdx.x & 63;
  size_t b = (size_t)row * 128;
  float a1 = pm1[b + lane], a2 = pm2[b + lane];
  int ai = pi1[b + lane];
  float b1 = pm1[b + lane + 64], b2 = pm2[b + lane + 64];
  int bi = pi1[b + lane + 64];
  float nm2 = fminf(fmaxf(a1, b1), fminf(a2, b2));
  if (b1 < a1 || (b1 == a1 && bi < ai)) { a1 = b1; ai = bi; }
  a2 = nm2;
#pragma unroll
  for (int off = 1; off < 64; off <<= 1) {
    float o1 = __shfl_xor(a1, off, 64);
    float o2 = __shfl_xor(a2, off, 64);
    int oi = __shfl_xor(ai, off, 64);
    float n2 = fminf(fmaxf(a1, o1), fminf(a2, o2));
    if (o1 < a1 || (o1 == a1 && oi < ai)) { a1 = o1; ai = oi; }
    a2 = n2;
  }
  if (lane == 0) {
    out_idx[row] = (float)ai;
    ws_idx[row] = ai;
    if (a2 - a1 < TAU) {
      int slot = atomicAdd(nflag, 1);
      flaglist[slot] = row;
    }
  }
}

// -------- pass 2: exact fp64 rescore of CANDIDATE halves only, flagged rows
// candidates = halves with pm1_half <= m1 + TAU (superset of any exact argmin)
__global__ __launch_bounds__(256) void vq_fixup(
    const float* __restrict__ zr, const float* __restrict__ zi,
    const float* __restrict__ w, const double* __restrict__ w2d,
    const float* __restrict__ pm1,
    const int* __restrict__ flaglist, const int* __restrict__ nflag,
    float* __restrict__ out_idx, int* __restrict__ ws_idx) {
  __shared__ float zrow[K];
  __shared__ float redf[128];
  __shared__ int cand[128];
  __shared__ int ncand_s;
  __shared__ double smin[64];
  __shared__ int sidx[64];
  const int tid = threadIdx.x;
  const int nf = *nflag;
  const int g4 = tid >> 2, sub = tid & 3;

  for (int f = blockIdx.x; f < nf; f += gridDim.x) {
    const int row = flaglist[f];
    __syncthreads();  // guard LDS reuse across grid-stride rows
    if (tid == 0) ncand_s = 0;
    for (int k = tid; k < K; k += 256)
      zrow[k] = (k < D) ? zr[(size_t)row * D + k] : zi[(size_t)row * D + (k - D)];
    float h = 3.4e38f;
    if (tid < 128) { h = pm1[(size_t)row * 128 + tid]; redf[tid] = h; }
    __syncthreads();
    for (int s = 64; s > 0; s >>= 1) {  // min over the 128 half-minima
      if (tid < s) redf[tid] = fminf(redf[tid], redf[tid + s]);
      __syncthreads();
    }
    const float m1 = redf[0];
    if (tid < 128 && h <= m1 + TAU) {
      int slot = atomicAdd(&ncand_s, 1);
      cand[slot] = tid;   // order scrambled; comparator below is order-independent
    }
    __syncthreads();
    const int nc = ncand_s;

    double best = 1e300;
    int bidx = 0x7fffffff;
    for (int ci = 0; ci < nc; ++ci) {
      const int v = cand[ci] * 64 + g4;   // 64 groups x 4 threads = one half
      const float4* wr4 = (const float4*)(w + (size_t)v * K + sub * 128);
      const float4* zl4 = (const float4*)(zrow + sub * 128);
      double d0 = 0.0, d1 = 0.0;
#pragma unroll
      for (int k4 = 0; k4 < 32; k4 += 2) {
        float4 a0 = wr4[k4], b0 = zl4[k4];
        float4 a1 = wr4[k4 + 1], b1 = zl4[k4 + 1];
        d0 = fma((double)a0.x, (double)b0.x, d0); d0 = fma((double)a0.y, (double)b0.y, d0);
        d0 = fma((double)a0.z, (double)b0.z, d0); d0 = fma((double)a0.w, (double)b0.w, d0);
        d1 = fma((double)a1.x, (double)b1.x, d1); d1 = fma((double)a1.y, (double)b1.y, d1);
        d1 = fma((double)a1.z, (double)b1.z, d1); d1 = fma((double)a1.w, (double)b1.w, d1);
      }
      double dot = d0 + d1;               // deterministic 4-lane combine
      dot += __shfl_xor(dot, 1, 64);
      dot += __shfl_xor(dot, 2, 64);
      double d = w2d[v] - 2.0 * dot;
      if (sub == 0 && (d < best || (d == best && v < bidx))) { best = d; bidx = v; }
    }
    if (sub == 0) { smin[g4] = best; sidx[g4] = bidx; }
    __syncthreads();
    for (int s = 32; s > 0; s >>= 1) {
      if (tid < s) {
        if (smin[tid + s] < smin[tid] ||
            (smin[tid + s] == smin[tid] && sidx[tid + s] < sidx[tid])) {
          smin[tid] = smin[tid + s];
          sidx[tid] = sidx[tid + s];
        }
      }
      __syncthreads();
    }
    if (tid == 0) { out_idx[row] = (float)sidx[0]; ws_idx[row] = sidx[0]; }
  }
}

// ---------------- gather z_q, write outputs 0/1, loss, histogram for entropy
__global__ __launch_bounds__(256) void vq_gather(
    const float* __restrict__ zr, const float* __restrict__ zi,
    const float* __restrict__ w, const int* __restrict__ ws_idx,
    float* __restrict__ out0, float* __restrict__ out1,
    float* __restrict__ out2, unsigned int* __restrict__ counts) {
  int row = blockIdx.x * 4 + (threadIdx.x >> 6);
  int lane = threadIdx.x & 63;
  int idx = ws_idx[row];
  const float4* wr = (const float4*)(w + (size_t)idx * K);
  float4 q0 = wr[lane];
  float4 q1 = wr[64 + lane];
  float4 a = ((const float4*)(zr + (size_t)row * D))[lane];
  float4 b = ((const float4*)(zi + (size_t)row * D))[lane];
  ((float4*)(out0 + (size_t)row * D))[lane] = q0;
  ((float4*)(out1 + (size_t)row * D))[lane] = q1;

  float s = 0.f, dx;
  dx = q0.x - a.x; s = fmaf(dx, dx, s);
  dx = q0.y - a.y; s = fmaf(dx, dx, s);
  dx = q0.z - a.z; s = fmaf(dx, dx, s);
  dx = q0.w - a.w; s = fmaf(dx, dx, s);
  dx = q1.x - b.x; s = fmaf(dx, dx, s);
  dx = q1.y - b.y; s = fmaf(dx, dx, s);
  dx = q1.z - b.z; s = fmaf(dx, dx, s);
  dx = q1.w - b.w; s = fmaf(dx, dx, s);
#pragma unroll
  for (int off = 1; off < 64; off <<= 1) s += __shfl_xor(s, off, 64);
  if (lane == 0) {
    out2[row] = s * (1.25f / 512.f);
    atomicAdd(counts + idx, 1u);
  }
}

// ------------------------------------------------------------------- entropy
__global__ __launch_bounds__(256) void vq_entropy(const unsigned int* __restrict__ counts,
                                                  float* __restrict__ out4) {
  __shared__ double sd[256];
  int tid = threadIdx.x;
  double e = 0.0;
  for (int v = tid; v < V; v += 256) {
    double p = (double)counts[v] * (1.0 / (double)N);
    e += p * log(p + 1e-10);
  }
  sd[tid] = e;
  __syncthreads();
  for (int s = 128; s > 0; s >>= 1) {
    if (tid < s) sd[tid] += sd[tid + s];
    __syncthreads();
  }
  if (tid == 0) *out4 = -(float)sd[0];
}

// ---------------------------------------------------------------------------
extern "C" void kernel_launch(void* const* d_in, const int* in_sizes, int n_in,
                              void* d_out, int out_size, void* d_ws, size_t ws_size,
                              hipStream_t stream) {
  const float* zr = (const float*)d_in[0];
  const float* zi = (const float*)d_in[1];
  const float* w = (const float*)d_in[2];

  float* out = (float*)d_out;
  float* out0 = out;                       // z_q real   (N*D)
  float* out1 = out + (size_t)N * D;       // z_q imag   (N*D)
  float* out2 = out + (size_t)2 * N * D;   // loss       (N)
  float* out3 = out2 + N;                  // indices    (N, as float)
  float* out4 = out3 + N;                  // entropy    (1)

  // top-2 partials live in the z_q output region; vq_gather overwrites it later
  float* pm1 = out;                              // N*128 floats = 8 MiB
  float* pm2 = out + (size_t)N * 128;            // 8 MiB
  int* pi1 = (int*)(out + (size_t)2 * N * 128);  // 8 MiB

  char* ws = (char*)d_ws;
  _Float16* Zf = (_Float16*)ws;                           // 16 MiB
  _Float16* Wf = (_Float16*)(ws + (((size_t)16) << 20));  // 8 MiB
  char* ws2 = ws + (((size_t)24) << 20);
  double* w2d = (double*)ws2;                          // 64 KiB
  float* w2f = (float*)(ws2 + 65536);                  // 32 KiB
  unsigned int* counts = (unsigned int*)(ws2 + 98304); // 32 KiB
  int* ws_idx = (int*)(ws2 + 131072);                  // 64 KiB
  int* flaglist = (int*)(ws2 + 196608);                // 64 KiB
  int* nflag = (int*)(ws2 + 262144);                   // 4 B

  (void)hipMemsetAsync(counts, 0, V * sizeof(unsigned int), stream);
  (void)hipMemsetAsync(nflag, 0, sizeof(int), stream);

  vq_cvt_z<<<N * 64 / 256, 256, 0, stream>>>(zr, zi, Zf);
  vq_cvt_w<<<V * 64 / 256, 256, 0, stream>>>(w, Wf);
  vq_w2<<<V / 4, 256, 0, stream>>>(w, w2d, w2f);
  vq_pass1<<<(N / 128) * (V / 128), 256, 0, stream>>>(Zf, Wf, w2f, pm1, pm2, pi1);
  vq_reduce<<<N / 4, 256, 0, stream>>>(pm1, pm2, pi1, out3, ws_idx, flaglist, nflag);
  vq_fixup<<<4096, 256, 0, stream>>>(zr, zi, w, w2d, pm1, flaglist, nflag, out3, ws_idx);
  vq_gather<<<N / 4, 256, 0, stream>>>(zr, zi, w, ws_idx, out0, out1, out2, counts);
  vq_entropy<<<1, 256, 0, stream>>>(counts, out4);
}